// Round 1
// baseline (428.357 us; speedup 1.0000x reference)
//
#include <hip/hip_runtime.h>
#include <hip/hip_bf16.h>

#define T_ 1024
#define H_ 1024
#define I_ 512
#define IS_ 2048
#define E_ 16

typedef __attribute__((ext_vector_type(8))) short short8;
typedef __attribute__((ext_vector_type(4))) float f32x4;

__device__ __forceinline__ unsigned short f2bf(float f) {
  unsigned u = __builtin_bit_cast(unsigned, f);
  unsigned r = (u + 0x7fffu + ((u >> 16) & 1u)) >> 16;
  return (unsigned short)r;
}

// ---------------- x fp32 -> bf16 ----------------
__global__ __launch_bounds__(256) void k_convert_x(const float* __restrict__ x,
                                                   unsigned short* __restrict__ xb) {
  long i = (long)blockIdx.x * 256 + threadIdx.x;
  float4 v = *(const float4*)(x + 4 * i);
  ushort4 o;
  o.x = f2bf(v.x); o.y = f2bf(v.y); o.z = f2bf(v.z); o.w = f2bf(v.w);
  *(ushort4*)(xb + 4 * i) = o;
}

// ------------- transpose + convert: src fp32 [b][R][C] -> dst bf16 [b][C][R] -------------
__global__ __launch_bounds__(256) void k_transpose_cvt(
    const float* __restrict__ src, unsigned short* __restrict__ dst,
    int R, int C, int dld, long sbs, long dbs) {
  __shared__ unsigned short tile[32 * 36];
  int b = blockIdx.z;
  const float* s = src + (long)b * sbs + ((long)blockIdx.y * 32) * C + blockIdx.x * 32;
  int r = threadIdx.x >> 3;
  int c4 = (threadIdx.x & 7) << 2;
  float4 v = *(const float4*)(s + (long)r * C + c4);
  tile[r * 36 + c4 + 0] = f2bf(v.x);
  tile[r * 36 + c4 + 1] = f2bf(v.y);
  tile[r * 36 + c4 + 2] = f2bf(v.z);
  tile[r * 36 + c4 + 3] = f2bf(v.w);
  __syncthreads();
  int oc = threadIdx.x >> 3;
  int orr = (threadIdx.x & 7) << 2;
  ushort4 o;
  o.x = tile[(orr + 0) * 36 + oc];
  o.y = tile[(orr + 1) * 36 + oc];
  o.z = tile[(orr + 2) * 36 + oc];
  o.w = tile[(orr + 3) * 36 + oc];
  unsigned short* d = dst + (long)b * dbs + (long)(blockIdx.x * 32 + oc) * dld + blockIdx.y * 32 + orr;
  *(ushort4*)d = o;
}

// ---------------- router: logits fp32, softmax, top4, renorm, shared gate ----------------
__global__ __launch_bounds__(64) void k_router(
    const float* __restrict__ x, const float* __restrict__ wr,
    const float* __restrict__ wshg, float* __restrict__ logits_out,
    int* __restrict__ top_i, float* __restrict__ top_w,
    int* __restrict__ counts, float* __restrict__ gate_sig) {
  int t = blockIdx.x, lane = threadIdx.x;
  float acc[17];
#pragma unroll
  for (int e = 0; e < 17; e++) acc[e] = 0.f;
  const float* xr = x + (long)t * H_;
  for (int h = lane; h < H_; h += 64) {
    float xv = xr[h];
    const float4* w4 = (const float4*)(wr + h * 16);
    float4 w0 = w4[0], w1 = w4[1], w2 = w4[2], w3 = w4[3];
    acc[0] += xv * w0.x; acc[1] += xv * w0.y; acc[2] += xv * w0.z; acc[3] += xv * w0.w;
    acc[4] += xv * w1.x; acc[5] += xv * w1.y; acc[6] += xv * w1.z; acc[7] += xv * w1.w;
    acc[8] += xv * w2.x; acc[9] += xv * w2.y; acc[10] += xv * w2.z; acc[11] += xv * w2.w;
    acc[12] += xv * w3.x; acc[13] += xv * w3.y; acc[14] += xv * w3.z; acc[15] += xv * w3.w;
    acc[16] += xv * wshg[h];
  }
#pragma unroll
  for (int off = 32; off >= 1; off >>= 1) {
#pragma unroll
    for (int e = 0; e < 17; e++) acc[e] += __shfl_xor(acc[e], off, 64);
  }
  if (lane == 0) {
    float m = acc[0];
#pragma unroll
    for (int e = 1; e < 16; e++) m = fmaxf(m, acc[e]);
    float p[16];
    float s = 0.f;
#pragma unroll
    for (int e = 0; e < 16; e++) { p[e] = expf(acc[e] - m); s += p[e]; }
    float inv = 1.f / s;
#pragma unroll
    for (int e = 0; e < 16; e++) p[e] *= inv;
    int ti[4]; float tw[4]; float tsum = 0.f;
#pragma unroll
    for (int k = 0; k < 4; k++) {
      float best = -1.f; int bi = 0;
#pragma unroll
      for (int e = 0; e < 16; e++) {
        if (p[e] > best) { best = p[e]; bi = e; }
      }
      ti[k] = bi; tw[k] = best; tsum += best; p[bi] = -2.f;
    }
    float rn = 1.f / tsum;
#pragma unroll
    for (int e = 0; e < 16; e++) logits_out[(long)t * 16 + e] = acc[e];
#pragma unroll
    for (int k = 0; k < 4; k++) {
      top_i[t * 4 + k] = ti[k];
      top_w[t * 4 + k] = tw[k] * rn;
      atomicAdd(&counts[ti[k]], 1);
    }
    gate_sig[t] = 1.f / (1.f + expf(-acc[16]));
  }
}

// ---------------- tiny scan ----------------
__global__ void k_scan(const int* __restrict__ counts, int* __restrict__ offsets,
                       int* __restrict__ cursors) {
  if (threadIdx.x == 0) {
    int run = 0;
    for (int e = 0; e < E_; e++) { offsets[e] = run; cursors[e] = run; run += counts[e]; }
  }
}

// ---------------- scatter: build perm / slot_of ----------------
__global__ __launch_bounds__(256) void k_scatter(
    const int* __restrict__ top_i, int* __restrict__ cursors,
    int* __restrict__ perm, int* __restrict__ slot_of) {
  int t = blockIdx.x * 256 + threadIdx.x;
  if (t < T_) {
#pragma unroll
    for (int k = 0; k < 4; k++) {
      int e = top_i[t * 4 + k];
      int pos = atomicAdd(&cursors[e], 1);
      perm[pos] = t;
      slot_of[t * 4 + k] = pos;
    }
  }
}

// ---------------- 128x128 MFMA GEMM, A[M][K] x B^T[N][K] -> Y[M][N] fp32 ----------------
template <bool GATHER>
__global__ __launch_bounds__(256) void k_gemm_bt(
    const unsigned short* __restrict__ A, int lda,
    const unsigned short* __restrict__ B, long b_stride, int ldb,
    float* __restrict__ Y, int ldy,
    int Mconst, int K,
    const int* __restrict__ counts, const int* __restrict__ offsets,
    const int* __restrict__ perm) {
  int M = Mconst;
  int row_base = 0;
  const unsigned short* Bq = B;
  if (counts) {
    int e = blockIdx.z;
    M = counts[e];
    row_base = offsets[e];
    Bq = B + (long)e * b_stride;
  }
  int mtile = blockIdx.y * 128;
  if (mtile >= M) return;
  int ntile = blockIdx.x * 128;

  __shared__ unsigned short As[128 * 40];
  __shared__ unsigned short Bs[128 * 40];

  int tid = threadIdx.x;
  int srow = tid >> 1;
  int sk = (tid & 1) << 4;

  int m_loc = mtile + srow;
  int m_cl = m_loc < M ? m_loc : M - 1;
  long a_row = GATHER ? (long)perm[row_base + m_cl] : (long)(row_base + m_cl);
  const unsigned short* a_src = A + a_row * (long)lda + sk;
  const unsigned short* b_src = Bq + (long)(ntile + srow) * ldb + sk;
  int lds_w = srow * 40 + sk;

  int wid = tid >> 6, lane = tid & 63;
  int wr = (wid >> 1) << 6, wc = (wid & 1) << 6;
  int fr = lane & 15, quad = lane >> 4;

  f32x4 acc[4][4];
#pragma unroll
  for (int i = 0; i < 4; i++)
#pragma unroll
    for (int j = 0; j < 4; j++) acc[i][j] = (f32x4){0.f, 0.f, 0.f, 0.f};

  for (int kt = 0; kt < K; kt += 32) {
    __syncthreads();
    uint4 av0 = *(const uint4*)(a_src + kt);
    uint4 av1 = *(const uint4*)(a_src + kt + 8);
    uint4 bv0 = *(const uint4*)(b_src + kt);
    uint4 bv1 = *(const uint4*)(b_src + kt + 8);
    *(uint4*)(&As[lds_w]) = av0;
    *(uint4*)(&As[lds_w + 8]) = av1;
    *(uint4*)(&Bs[lds_w]) = bv0;
    *(uint4*)(&Bs[lds_w + 8]) = bv1;
    __syncthreads();
    short8 af[4], bf[4];
#pragma unroll
    for (int i = 0; i < 4; i++)
      af[i] = *(const short8*)(&As[(wr + i * 16 + fr) * 40 + quad * 8]);
#pragma unroll
    for (int j = 0; j < 4; j++)
      bf[j] = *(const short8*)(&Bs[(wc + j * 16 + fr) * 40 + quad * 8]);
#pragma unroll
    for (int i = 0; i < 4; i++)
#pragma unroll
      for (int j = 0; j < 4; j++)
        acc[i][j] = __builtin_amdgcn_mfma_f32_16x16x32_bf16(af[i], bf[j], acc[i][j], 0, 0, 0);
  }

#pragma unroll
  for (int i = 0; i < 4; i++) {
    int m0 = mtile + wr + i * 16 + quad * 4;
#pragma unroll
    for (int j = 0; j < 4; j++) {
      int col = ntile + wc + j * 16 + fr;
#pragma unroll
      for (int r = 0; r < 4; r++) {
        int m = m0 + r;
        if (m < M) Y[(long)(row_base + m) * ldy + col] = acc[i][j][r];
      }
    }
  }
}

// ---------------- epilogue: h = silu(g)*u, Y[rows][2N] -> bf16 [rows][N] ----------------
__global__ __launch_bounds__(256) void k_silu_mul(const float* __restrict__ Y,
                                                  unsigned short* __restrict__ Hd,
                                                  int rows, int N) {
  long idx = (long)blockIdx.x * 256 + threadIdx.x;
  long n4 = N >> 2;
  long total = (long)rows * n4;
  if (idx >= total) return;
  long r = idx / n4;
  long c = (idx - r * n4) << 2;
  const float* yr = Y + r * 2 * N;
  float4 g = *(const float4*)(yr + c);
  float4 u = *(const float4*)(yr + N + c);
  ushort4 o;
  o.x = f2bf(g.x / (1.f + expf(-g.x)) * u.x);
  o.y = f2bf(g.y / (1.f + expf(-g.y)) * u.y);
  o.z = f2bf(g.z / (1.f + expf(-g.z)) * u.z);
  o.w = f2bf(g.w / (1.f + expf(-g.w)) * u.w);
  *(ushort4*)(Hd + r * N + c) = o;
}

// ---------------- combine: out = sum_k w*Yd[slot] + sig*shared ----------------
__global__ __launch_bounds__(256) void k_combine(
    const float* __restrict__ Yd, const float* __restrict__ shout,
    const float* __restrict__ gate_sig, const float* __restrict__ top_w,
    const int* __restrict__ slot_of, float* __restrict__ out) {
  int t = blockIdx.x;
  int c = threadIdx.x << 2;
  float4 sh = *(const float4*)(shout + (long)t * H_ + c);
  float gs = gate_sig[t];
  float4 o;
  o.x = gs * sh.x; o.y = gs * sh.y; o.z = gs * sh.z; o.w = gs * sh.w;
#pragma unroll
  for (int k = 0; k < 4; k++) {
    int s = slot_of[t * 4 + k];
    float w = top_w[t * 4 + k];
    float4 v = *(const float4*)(Yd + (long)s * H_ + c);
    o.x += w * v.x; o.y += w * v.y; o.z += w * v.z; o.w += w * v.w;
  }
  *(float4*)(out + (long)t * H_ + c) = o;
}

extern "C" void kernel_launch(void* const* d_in, const int* in_sizes, int n_in,
                              void* d_out, int out_size, void* d_ws, size_t ws_size,
                              hipStream_t stream) {
  const float* x    = (const float*)d_in[0];
  const float* wrt  = (const float*)d_in[1];
  const float* wg   = (const float*)d_in[2];
  const float* wu   = (const float*)d_in[3];
  const float* wd   = (const float*)d_in[4];
  const float* wsg  = (const float*)d_in[5];
  const float* wsu  = (const float*)d_in[6];
  const float* wsd  = (const float*)d_in[7];
  const float* wshg = (const float*)d_in[8];
  float* out = (float*)d_out;
  float* logits_out = out + (long)T_ * H_;

  char* ws = (char*)d_ws;
  size_t off = 0;
  auto take = [&](size_t bytes) -> void* {
    void* p = ws + off;
    off += (bytes + 255) & ~(size_t)255;
    return p;
  };

  unsigned short* XB    = (unsigned short*)take((size_t)T_ * H_ * 2);
  unsigned short* WGUT  = (unsigned short*)take((size_t)E_ * 2 * I_ * H_ * 2);  // [e][n=2I][h]
  unsigned short* WDT   = (unsigned short*)take((size_t)E_ * H_ * I_ * 2);      // [e][n=H][k=I]
  unsigned short* WSGUT = (unsigned short*)take((size_t)2 * IS_ * H_ * 2);      // [n=2IS][h]
  unsigned short* WSDT  = (unsigned short*)take((size_t)H_ * IS_ * 2);          // [n=H][k=IS]
  float*          YBUF  = (float*)take((size_t)4096 * 1024 * 4);                // reused 3x
  unsigned short* HSB   = (unsigned short*)take((size_t)T_ * IS_ * 2);
  float*          SHOUT = (float*)take((size_t)T_ * H_ * 4);
  unsigned short* HB    = (unsigned short*)take((size_t)4096 * I_ * 2);
  int*   counts   = (int*)take(64);
  int*   offsets  = (int*)take(64);
  int*   cursors  = (int*)take(64);
  int*   top_i    = (int*)take((size_t)T_ * 4 * 4);
  float* top_w    = (float*)take((size_t)T_ * 4 * 4);
  int*   perm     = (int*)take((size_t)4096 * 4);
  int*   slot_of  = (int*)take((size_t)4096 * 4);
  float* gate_sig = (float*)take((size_t)T_ * 4);

  hipMemsetAsync(counts, 0, 64, stream);
  k_convert_x<<<T_ * H_ / 1024, 256, 0, stream>>>(x, XB);

  // weight transposes to [N][K] bf16
  k_transpose_cvt<<<dim3(I_ / 32, H_ / 32, E_), 256, 0, stream>>>(
      wg, WGUT, H_, I_, H_, (long)H_ * I_, (long)2 * I_ * H_);
  k_transpose_cvt<<<dim3(I_ / 32, H_ / 32, E_), 256, 0, stream>>>(
      wu, WGUT + (size_t)I_ * H_, H_, I_, H_, (long)H_ * I_, (long)2 * I_ * H_);
  k_transpose_cvt<<<dim3(H_ / 32, I_ / 32, E_), 256, 0, stream>>>(
      wd, WDT, I_, H_, I_, (long)I_ * H_, (long)H_ * I_);
  k_transpose_cvt<<<dim3(IS_ / 32, H_ / 32, 1), 256, 0, stream>>>(
      wsg, WSGUT, H_, IS_, H_, 0, 0);
  k_transpose_cvt<<<dim3(IS_ / 32, H_ / 32, 1), 256, 0, stream>>>(
      wsu, WSGUT + (size_t)IS_ * H_, H_, IS_, H_, 0, 0);
  k_transpose_cvt<<<dim3(H_ / 32, IS_ / 32, 1), 256, 0, stream>>>(
      wsd, WSDT, IS_, H_, IS_, 0, 0);

  k_router<<<T_, 64, 0, stream>>>(x, wrt, wshg, logits_out, top_i, top_w, counts, gate_sig);
  k_scan<<<1, 64, 0, stream>>>(counts, offsets, cursors);
  k_scatter<<<(T_ + 255) / 256, 256, 0, stream>>>(top_i, cursors, perm, slot_of);

  // shared gate/up: M=1024, N=4096, K=1024 -> YBUF [1024][4096]
  k_gemm_bt<false><<<dim3(4096 / 128, 1024 / 128, 1), 256, 0, stream>>>(
      XB, H_, WSGUT, 0, H_, YBUF, 4096, T_, H_, nullptr, nullptr, nullptr);
  k_silu_mul<<<2048, 256, 0, stream>>>(YBUF, HSB, T_, IS_);

  // shared down: M=1024, N=1024, K=2048 -> SHOUT
  k_gemm_bt<false><<<dim3(1024 / 128, 1024 / 128, 1), 256, 0, stream>>>(
      HSB, IS_, WSDT, 0, IS_, SHOUT, H_, T_, IS_, nullptr, nullptr, nullptr);

  // expert gate/up (gathered rows): N=1024, K=1024 -> YBUF [4096 slots][1024]
  k_gemm_bt<true><<<dim3(1024 / 128, 8, E_), 256, 0, stream>>>(
      XB, H_, WGUT, (long)2 * I_ * H_, H_, YBUF, 1024, 0, H_, counts, offsets, perm);
  k_silu_mul<<<2048, 256, 0, stream>>>(YBUF, HB, 4096, I_);

  // expert down: N=1024, K=512 -> YBUF [4096 slots][1024]
  k_gemm_bt<false><<<dim3(1024 / 128, 8, E_), 256, 0, stream>>>(
      HB, I_, WDT, (long)H_ * I_, I_, YBUF, 1024, 0, I_, counts, offsets, perm);

  k_combine<<<T_, 256, 0, stream>>>(YBUF, SHOUT, gate_sig, top_w, slot_of, out);
}

// Round 2
// 400.319 us; speedup vs baseline: 1.0700x; 1.0700x over previous
//
#include <hip/hip_runtime.h>
#include <hip/hip_bf16.h>

#define T_ 1024
#define H_ 1024
#define I_ 512
#define IS_ 2048
#define E_ 16

typedef __attribute__((ext_vector_type(8))) short short8;
typedef __attribute__((ext_vector_type(4))) float f32x4;

__device__ __forceinline__ unsigned short f2bf(float f) {
  unsigned u = __builtin_bit_cast(unsigned, f);
  unsigned r = (u + 0x7fffu + ((u >> 16) & 1u)) >> 16;
  return (unsigned short)r;
}

__device__ __forceinline__ void gload16(const void* g, void* l) {
  __builtin_amdgcn_global_load_lds(
      (const __attribute__((address_space(1))) unsigned int*)g,
      (__attribute__((address_space(3))) unsigned int*)l, 16, 0, 0);
}

// ---------------- x fp32 -> bf16 ----------------
__global__ __launch_bounds__(256) void k_convert_x(const float* __restrict__ x,
                                                   unsigned short* __restrict__ xb) {
  long i = (long)blockIdx.x * 256 + threadIdx.x;
  float4 v = *(const float4*)(x + 4 * i);
  ushort4 o;
  o.x = f2bf(v.x); o.y = f2bf(v.y); o.z = f2bf(v.z); o.w = f2bf(v.w);
  *(ushort4*)(xb + 4 * i) = o;
}

// ------------- transpose + convert: src fp32 [b][R][C] -> dst bf16 [b][C][R] -------------
// 64x64 tiles. LDS holds the tile already transposed: tile[src_col][src_row].
__global__ __launch_bounds__(256) void k_transpose_cvt(
    const float* __restrict__ src, unsigned short* __restrict__ dst,
    int C, int dld, long sbs, long dbs) {
  __shared__ unsigned short tile[64 * 72];
  int b = blockIdx.z;
  const float* s = src + (long)b * sbs + ((long)blockIdx.y * 64) * C + blockIdx.x * 64;
  int r = threadIdx.x >> 4;          // 0..15
  int c = (threadIdx.x & 15) << 2;   // 0..60
#pragma unroll
  for (int p = 0; p < 4; p++) {
    int sr = r + p * 16;
    float4 v = *(const float4*)(s + (long)sr * C + c);
    tile[(c + 0) * 72 + sr] = f2bf(v.x);
    tile[(c + 1) * 72 + sr] = f2bf(v.y);
    tile[(c + 2) * 72 + sr] = f2bf(v.z);
    tile[(c + 3) * 72 + sr] = f2bf(v.w);
  }
  __syncthreads();
  int orr = threadIdx.x >> 2;        // 0..63 (dst row = src col)
  int ks = (threadIdx.x & 3) << 4;   // 0..48
  uint4 o0 = *(const uint4*)&tile[orr * 72 + ks];
  uint4 o1 = *(const uint4*)&tile[orr * 72 + ks + 8];
  unsigned short* d = dst + (long)b * dbs + (long)(blockIdx.x * 64 + orr) * dld +
                      blockIdx.y * 64 + ks;
  *(uint4*)d = o0;
  *(uint4*)(d + 8) = o1;
}

// ---------------- router: logits fp32, softmax, top4, renorm, shared gate ----------------
__global__ __launch_bounds__(256) void k_router(
    const float* __restrict__ x, const float* __restrict__ wr,
    const float* __restrict__ wshg, float* __restrict__ logits_out,
    int* __restrict__ top_i, float* __restrict__ top_w,
    int* __restrict__ counts, float* __restrict__ gate_sig) {
  __shared__ float red[4][17];
  int t = blockIdx.x, tid = threadIdx.x;
  int h0 = tid << 2;
  float acc[17];
#pragma unroll
  for (int e = 0; e < 17; e++) acc[e] = 0.f;
  float4 xv = *(const float4*)(x + (long)t * H_ + h0);
  float4 wsh = *(const float4*)(wshg + h0);
  float xs[4] = {xv.x, xv.y, xv.z, xv.w};
  float ws[4] = {wsh.x, wsh.y, wsh.z, wsh.w};
#pragma unroll
  for (int j = 0; j < 4; j++) {
    const float4* w4 = (const float4*)(wr + (long)(h0 + j) * 16);
    float4 w0 = w4[0], w1 = w4[1], w2 = w4[2], w3 = w4[3];
    float xvj = xs[j];
    acc[0] += xvj * w0.x; acc[1] += xvj * w0.y; acc[2] += xvj * w0.z; acc[3] += xvj * w0.w;
    acc[4] += xvj * w1.x; acc[5] += xvj * w1.y; acc[6] += xvj * w1.z; acc[7] += xvj * w1.w;
    acc[8] += xvj * w2.x; acc[9] += xvj * w2.y; acc[10] += xvj * w2.z; acc[11] += xvj * w2.w;
    acc[12] += xvj * w3.x; acc[13] += xvj * w3.y; acc[14] += xvj * w3.z; acc[15] += xvj * w3.w;
    acc[16] += xvj * ws[j];
  }
#pragma unroll
  for (int off = 32; off >= 1; off >>= 1) {
#pragma unroll
    for (int e = 0; e < 17; e++) acc[e] += __shfl_xor(acc[e], off, 64);
  }
  int wid = tid >> 6, lane = tid & 63;
  if (lane == 0) {
#pragma unroll
    for (int e = 0; e < 17; e++) red[wid][e] = acc[e];
  }
  __syncthreads();
  if (tid == 0) {
    float a[17];
#pragma unroll
    for (int e = 0; e < 17; e++)
      a[e] = red[0][e] + red[1][e] + red[2][e] + red[3][e];
    float m = a[0];
#pragma unroll
    for (int e = 1; e < 16; e++) m = fmaxf(m, a[e]);
    float p[16], s = 0.f;
#pragma unroll
    for (int e = 0; e < 16; e++) { p[e] = expf(a[e] - m); s += p[e]; }
    float inv = 1.f / s;
#pragma unroll
    for (int e = 0; e < 16; e++) p[e] *= inv;
    int ti[4]; float tw[4]; float tsum = 0.f;
#pragma unroll
    for (int k = 0; k < 4; k++) {
      float best = -1.f; int bi = 0;
#pragma unroll
      for (int e = 0; e < 16; e++)
        if (p[e] > best) { best = p[e]; bi = e; }
      ti[k] = bi; tw[k] = best; tsum += best; p[bi] = -2.f;
    }
    float rn = 1.f / tsum;
#pragma unroll
    for (int e = 0; e < 16; e++) logits_out[(long)t * 16 + e] = a[e];
#pragma unroll
    for (int k = 0; k < 4; k++) {
      top_i[t * 4 + k] = ti[k];
      top_w[t * 4 + k] = tw[k] * rn;
      atomicAdd(&counts[ti[k]], 1);
    }
    gate_sig[t] = 1.f / (1.f + expf(-a[16]));
  }
}

// ---------------- tiny scan ----------------
__global__ void k_scan(const int* __restrict__ counts, int* __restrict__ offsets,
                       int* __restrict__ cursors) {
  if (threadIdx.x == 0) {
    int run = 0;
    for (int e = 0; e < E_; e++) { offsets[e] = run; cursors[e] = run; run += counts[e]; }
  }
}

// ---------------- scatter: build perm / slot_of ----------------
__global__ __launch_bounds__(256) void k_scatter(
    const int* __restrict__ top_i, int* __restrict__ cursors,
    int* __restrict__ perm, int* __restrict__ slot_of) {
  int t = blockIdx.x * 256 + threadIdx.x;
  if (t < T_) {
#pragma unroll
    for (int k = 0; k < 4; k++) {
      int e = top_i[t * 4 + k];
      int pos = atomicAdd(&cursors[e], 1);
      perm[pos] = t;
      slot_of[t * 4 + k] = pos;
    }
  }
}

// ---------------- m97-style MFMA GEMM: A[M][K] x B^T[N][K] -> Y[M][N] fp32 ----------------
// BM=128 fixed; BN in {128, 64}. global_load_lds staging into unpadded [row][32] LDS.
template <int BN, bool GATHER>
__global__ __launch_bounds__(256) void k_gemm(
    const unsigned short* __restrict__ A, int lda,
    const unsigned short* __restrict__ B, long b_stride, int ldb,
    float* __restrict__ Y, int ldy,
    int Mconst, int K,
    const int* __restrict__ counts, const int* __restrict__ offsets,
    const int* __restrict__ perm) {
  int M = Mconst, row_base = 0;
  const unsigned short* Bq = B;
  if (counts) {
    int e = blockIdx.z;
    M = counts[e];
    row_base = offsets[e];
    Bq = B + (long)e * b_stride;
  }
  int mtile = blockIdx.y * 128;
  if (mtile >= M) return;
  int ntile = blockIdx.x * BN;

  __shared__ unsigned short As[128 * 32];
  __shared__ unsigned short Bs[BN * 32];

  int tid = threadIdx.x;
  int wid = tid >> 6, lane = tid & 63;
  int sub = lane >> 2;            // 0..15
  int ks = (lane & 3) << 3;       // shorts, 0/8/16/24

  // A staging: 2 issues of 16B per lane cover 128 rows x 32 k
  const unsigned short* aptr[2];
  unsigned short* alds[2];
#pragma unroll
  for (int q = 0; q < 2; q++) {
    int r = q * 64 + wid * 16 + sub;
    int rm = mtile + r;
    if (rm > M - 1) rm = M - 1;
    long arow = GATHER ? (long)perm[row_base + rm] : (long)(row_base + rm);
    aptr[q] = A + arow * (long)lda + ks;
    alds[q] = As + q * 2048 + wid * 512;   // uniform per wave
  }
  // B staging: BN/64 issues
  constexpr int BQ = BN / 64;
  const unsigned short* bptr[BQ];
  unsigned short* blds[BQ];
#pragma unroll
  for (int q = 0; q < BQ; q++) {
    int r = q * 64 + wid * 16 + sub;
    bptr[q] = Bq + (long)(ntile + r) * ldb + ks;
    blds[q] = Bs + q * 2048 + wid * 512;
  }

  constexpr int MI = (BN == 128) ? 4 : 2;
  int wr = (BN == 128) ? ((wid >> 1) << 6) : (wid << 5);
  int wc = (BN == 128) ? ((wid & 1) << 6) : 0;
  int fr = lane & 15, quad = lane >> 4;

  f32x4 acc[MI][4];
#pragma unroll
  for (int i = 0; i < MI; i++)
#pragma unroll
    for (int j = 0; j < 4; j++) acc[i][j] = (f32x4){0.f, 0.f, 0.f, 0.f};

  for (int kt = 0; kt < K; kt += 32) {
    __syncthreads();
#pragma unroll
    for (int q = 0; q < 2; q++) gload16(aptr[q] + kt, alds[q]);
#pragma unroll
    for (int q = 0; q < BQ; q++) gload16(bptr[q] + kt, blds[q]);
    __syncthreads();
    short8 af[MI], bf[4];
#pragma unroll
    for (int i = 0; i < MI; i++)
      af[i] = *(const short8*)(&As[(wr + i * 16 + fr) * 32 + quad * 8]);
#pragma unroll
    for (int j = 0; j < 4; j++)
      bf[j] = *(const short8*)(&Bs[(wc + j * 16 + fr) * 32 + quad * 8]);
#pragma unroll
    for (int i = 0; i < MI; i++)
#pragma unroll
      for (int j = 0; j < 4; j++)
        acc[i][j] = __builtin_amdgcn_mfma_f32_16x16x32_bf16(af[i], bf[j], acc[i][j], 0, 0, 0);
  }

#pragma unroll
  for (int i = 0; i < MI; i++) {
    int m0 = mtile + wr + i * 16 + quad * 4;
#pragma unroll
    for (int j = 0; j < 4; j++) {
      int col = ntile + wc + j * 16 + fr;
#pragma unroll
      for (int r = 0; r < 4; r++) {
        int m = m0 + r;
        if (m < M) Y[(long)(row_base + m) * ldy + col] = acc[i][j][r];
      }
    }
  }
}

// ---------------- epilogue: h = silu(g)*u, Y[rows][2N] -> bf16 [rows][N] ----------------
__global__ __launch_bounds__(256) void k_silu_mul(const float* __restrict__ Y,
                                                  unsigned short* __restrict__ Hd,
                                                  int rows, int N) {
  long idx = (long)blockIdx.x * 256 + threadIdx.x;
  long n4 = N >> 2;
  long total = (long)rows * n4;
  if (idx >= total) return;
  long r = idx / n4;
  long c = (idx - r * n4) << 2;
  const float* yr = Y + r * 2 * N;
  float4 g = *(const float4*)(yr + c);
  float4 u = *(const float4*)(yr + N + c);
  ushort4 o;
  o.x = f2bf(g.x / (1.f + expf(-g.x)) * u.x);
  o.y = f2bf(g.y / (1.f + expf(-g.y)) * u.y);
  o.z = f2bf(g.z / (1.f + expf(-g.z)) * u.z);
  o.w = f2bf(g.w / (1.f + expf(-g.w)) * u.w);
  *(ushort4*)(Hd + r * N + c) = o;
}

// ---------------- combine: out = sum_k w*Yd[slot] + sig*shared ----------------
__global__ __launch_bounds__(256) void k_combine(
    const float* __restrict__ Yd, const float* __restrict__ shout,
    const float* __restrict__ gate_sig, const float* __restrict__ top_w,
    const int* __restrict__ slot_of, float* __restrict__ out) {
  int t = blockIdx.x;
  int c = threadIdx.x << 2;
  float4 sh = *(const float4*)(shout + (long)t * H_ + c);
  float gs = gate_sig[t];
  float4 o;
  o.x = gs * sh.x; o.y = gs * sh.y; o.z = gs * sh.z; o.w = gs * sh.w;
#pragma unroll
  for (int k = 0; k < 4; k++) {
    int s = slot_of[t * 4 + k];
    float w = top_w[t * 4 + k];
    float4 v = *(const float4*)(Yd + (long)s * H_ + c);
    o.x += w * v.x; o.y += w * v.y; o.z += w * v.z; o.w += w * v.w;
  }
  *(float4*)(out + (long)t * H_ + c) = o;
}

extern "C" void kernel_launch(void* const* d_in, const int* in_sizes, int n_in,
                              void* d_out, int out_size, void* d_ws, size_t ws_size,
                              hipStream_t stream) {
  const float* x    = (const float*)d_in[0];
  const float* wrt  = (const float*)d_in[1];
  const float* wg   = (const float*)d_in[2];
  const float* wu   = (const float*)d_in[3];
  const float* wd   = (const float*)d_in[4];
  const float* wsg  = (const float*)d_in[5];
  const float* wsu  = (const float*)d_in[6];
  const float* wsd  = (const float*)d_in[7];
  const float* wshg = (const float*)d_in[8];
  float* out = (float*)d_out;
  float* logits_out = out + (long)T_ * H_;

  char* ws = (char*)d_ws;
  size_t off = 0;
  auto take = [&](size_t bytes) -> void* {
    void* p = ws + off;
    off += (bytes + 255) & ~(size_t)255;
    return p;
  };

  unsigned short* XB    = (unsigned short*)take((size_t)T_ * H_ * 2);
  unsigned short* WGUT  = (unsigned short*)take((size_t)E_ * 2 * I_ * H_ * 2);  // [e][n=2I][h]
  unsigned short* WDT   = (unsigned short*)take((size_t)E_ * H_ * I_ * 2);      // [e][n=H][k=I]
  unsigned short* WSGUT = (unsigned short*)take((size_t)2 * IS_ * H_ * 2);      // [n=2IS][h]
  unsigned short* WSDT  = (unsigned short*)take((size_t)H_ * IS_ * 2);          // [n=H][k=IS]
  float*          YBUF  = (float*)take((size_t)4096 * 1024 * 4);                // reused 3x
  unsigned short* HSB   = (unsigned short*)take((size_t)T_ * IS_ * 2);
  float*          SHOUT = (float*)take((size_t)T_ * H_ * 4);
  unsigned short* HB    = (unsigned short*)take((size_t)4096 * I_ * 2);
  int*   counts   = (int*)take(64);
  int*   offsets  = (int*)take(64);
  int*   cursors  = (int*)take(64);
  int*   top_i    = (int*)take((size_t)T_ * 4 * 4);
  float* top_w    = (float*)take((size_t)T_ * 4 * 4);
  int*   perm     = (int*)take((size_t)4096 * 4);
  int*   slot_of  = (int*)take((size_t)4096 * 4);
  float* gate_sig = (float*)take((size_t)T_ * 4);

  hipMemsetAsync(counts, 0, 64, stream);
  k_convert_x<<<T_ * H_ / 1024, 256, 0, stream>>>(x, XB);

  // weight transposes to [N][K] bf16 (64x64 tiles)
  k_transpose_cvt<<<dim3(I_ / 64, H_ / 64, E_), 256, 0, stream>>>(
      wg, WGUT, I_, H_, (long)H_ * I_, (long)2 * I_ * H_);
  k_transpose_cvt<<<dim3(I_ / 64, H_ / 64, E_), 256, 0, stream>>>(
      wu, WGUT + (size_t)I_ * H_, I_, H_, (long)H_ * I_, (long)2 * I_ * H_);
  k_transpose_cvt<<<dim3(H_ / 64, I_ / 64, E_), 256, 0, stream>>>(
      wd, WDT, H_, I_, (long)I_ * H_, (long)H_ * I_);
  k_transpose_cvt<<<dim3(IS_ / 64, H_ / 64, 1), 256, 0, stream>>>(
      wsg, WSGUT, IS_, H_, 0, 0);
  k_transpose_cvt<<<dim3(IS_ / 64, H_ / 64, 1), 256, 0, stream>>>(
      wsu, WSGUT + (size_t)IS_ * H_, IS_, H_, 0, 0);
  k_transpose_cvt<<<dim3(H_ / 64, IS_ / 64, 1), 256, 0, stream>>>(
      wsd, WSDT, H_, IS_, 0, 0);

  k_router<<<T_, 256, 0, stream>>>(x, wrt, wshg, logits_out, top_i, top_w, counts, gate_sig);
  k_scan<<<1, 64, 0, stream>>>(counts, offsets, cursors);
  k_scatter<<<(T_ + 255) / 256, 256, 0, stream>>>(top_i, cursors, perm, slot_of);

  // shared gate/up: M=1024, N=4096, K=1024 -> YBUF [1024][4096]
  k_gemm<128, false><<<dim3(4096 / 128, 1024 / 128, 1), 256, 0, stream>>>(
      XB, H_, WSGUT, 0, H_, YBUF, 4096, T_, H_, nullptr, nullptr, nullptr);
  k_silu_mul<<<2048, 256, 0, stream>>>(YBUF, HSB, T_, IS_);

  // shared down: M=1024, N=1024, K=2048 -> SHOUT  (BN=64 for 2x the blocks)
  k_gemm<64, false><<<dim3(1024 / 64, 1024 / 128, 1), 256, 0, stream>>>(
      HSB, IS_, WSDT, 0, IS_, SHOUT, H_, T_, IS_, nullptr, nullptr, nullptr);

  // expert gate/up (gathered rows): N=1024, K=1024 -> YBUF [4096 slots][1024]
  k_gemm<128, true><<<dim3(1024 / 128, 8, E_), 256, 0, stream>>>(
      XB, H_, WGUT, (long)2 * I_ * H_, H_, YBUF, 1024, 0, H_, counts, offsets, perm);
  k_silu_mul<<<2048, 256, 0, stream>>>(YBUF, HB, 4096, I_);

  // expert down: N=1024, K=512 -> YBUF [4096 slots][1024]
  k_gemm<128, false><<<dim3(1024 / 128, 8, E_), 256, 0, stream>>>(
      HB, I_, WDT, (long)H_ * I_, I_, YBUF, 1024, 0, I_, counts, offsets, perm);

  k_combine<<<T_, 256, 0, stream>>>(YBUF, SHOUT, gate_sig, top_w, slot_of, out);
}

// Round 4
// 348.769 us; speedup vs baseline: 1.2282x; 1.1478x over previous
//
#include <hip/hip_runtime.h>
#include <hip/hip_bf16.h>

#define T_ 1024
#define H_ 1024
#define I_ 512
#define IS_ 2048
#define E_ 16

typedef __attribute__((ext_vector_type(8))) short short8;
typedef __attribute__((ext_vector_type(4))) float f32x4;

__device__ __forceinline__ unsigned short f2bf(float f) {
  unsigned u = __builtin_bit_cast(unsigned, f);
  unsigned r = (u + 0x7fffu + ((u >> 16) & 1u)) >> 16;
  return (unsigned short)r;
}

__device__ __forceinline__ void gload16(const void* g, void* l) {
  __builtin_amdgcn_global_load_lds(
      (const __attribute__((address_space(1))) unsigned int*)g,
      (__attribute__((address_space(3))) unsigned int*)l, 16, 0, 0);
}

// ------------- transpose + convert: src fp32 [b][R][C] -> dst bf16 [b][C][R] -------------
// 64x64 tile, 4x4 register micro-transpose, b64 LDS writes, PAD=72 (16B-aligned b128 reads).
// NOTE: read side must cover ks..ks+15 (two uint4s) — dropping the second half was the
// round-3 correctness bug (half of every weight tile left unwritten).
__global__ __launch_bounds__(256) void k_transpose_cvt(
    const float* __restrict__ src, unsigned short* __restrict__ dst,
    int C, int dld, long sbs, long dbs) {
  __shared__ unsigned short tile[64 * 72];
  int b = blockIdx.z;
  const float* s = src + (long)b * sbs + ((long)blockIdx.y * 64) * C + blockIdx.x * 64;
  int cgrp = threadIdx.x & 15, rgrp = threadIdx.x >> 4;
  int c = cgrp << 2, r0 = rgrp << 2;
  const float* sp = s + (long)r0 * C + c;
  float4 v0 = *(const float4*)(sp);
  float4 v1 = *(const float4*)(sp + C);
  float4 v2 = *(const float4*)(sp + 2 * C);
  float4 v3 = *(const float4*)(sp + 3 * C);
  ushort4 w;
  w = (ushort4){f2bf(v0.x), f2bf(v1.x), f2bf(v2.x), f2bf(v3.x)};
  *(ushort4*)&tile[(c + 0) * 72 + r0] = w;
  w = (ushort4){f2bf(v0.y), f2bf(v1.y), f2bf(v2.y), f2bf(v3.y)};
  *(ushort4*)&tile[(c + 1) * 72 + r0] = w;
  w = (ushort4){f2bf(v0.z), f2bf(v1.z), f2bf(v2.z), f2bf(v3.z)};
  *(ushort4*)&tile[(c + 2) * 72 + r0] = w;
  w = (ushort4){f2bf(v0.w), f2bf(v1.w), f2bf(v2.w), f2bf(v3.w)};
  *(ushort4*)&tile[(c + 3) * 72 + r0] = w;
  __syncthreads();
  int orr = threadIdx.x >> 2;        // dst row (src col)
  int ks = (threadIdx.x & 3) << 4;   // dst col chunk (16 shorts per thread)
  uint4 o0 = *(const uint4*)&tile[orr * 72 + ks];
  uint4 o1 = *(const uint4*)&tile[orr * 72 + ks + 8];
  unsigned short* d = dst + (long)b * dbs + (long)(blockIdx.x * 64 + orr) * dld +
                      blockIdx.y * 64 + ks;
  *(uint4*)d = o0;
  *(uint4*)(d + 8) = o1;
}

// ------- router: logits fp32, softmax, top4, renorm, shared gate; fused x->bf16 -------
// NO global atomics (they serialized the whole kernel: 4096 same-line atomics ~57us).
__global__ __launch_bounds__(256) void k_router(
    const float* __restrict__ x, const float* __restrict__ wr,
    const float* __restrict__ wshg, unsigned short* __restrict__ xb,
    float* __restrict__ logits_out,
    int* __restrict__ top_i, float* __restrict__ top_w,
    float* __restrict__ gate_sig) {
  __shared__ float red[4][17];
  int t = blockIdx.x, tid = threadIdx.x;
  int h0 = tid << 2;
  float acc[17];
#pragma unroll
  for (int e = 0; e < 17; e++) acc[e] = 0.f;
  float4 xv = *(const float4*)(x + (long)t * H_ + h0);
  float4 wsh = *(const float4*)(wshg + h0);
  // fused bf16 conversion of x
  ushort4 xo;
  xo.x = f2bf(xv.x); xo.y = f2bf(xv.y); xo.z = f2bf(xv.z); xo.w = f2bf(xv.w);
  *(ushort4*)(xb + (long)t * H_ + h0) = xo;
  float xs[4] = {xv.x, xv.y, xv.z, xv.w};
  float ws[4] = {wsh.x, wsh.y, wsh.z, wsh.w};
#pragma unroll
  for (int j = 0; j < 4; j++) {
    const float4* w4 = (const float4*)(wr + (long)(h0 + j) * 16);
    float4 w0 = w4[0], w1 = w4[1], w2 = w4[2], w3 = w4[3];
    float xvj = xs[j];
    acc[0] += xvj * w0.x; acc[1] += xvj * w0.y; acc[2] += xvj * w0.z; acc[3] += xvj * w0.w;
    acc[4] += xvj * w1.x; acc[5] += xvj * w1.y; acc[6] += xvj * w1.z; acc[7] += xvj * w1.w;
    acc[8] += xvj * w2.x; acc[9] += xvj * w2.y; acc[10] += xvj * w2.z; acc[11] += xvj * w2.w;
    acc[12] += xvj * w3.x; acc[13] += xvj * w3.y; acc[14] += xvj * w3.z; acc[15] += xvj * w3.w;
    acc[16] += xvj * ws[j];
  }
#pragma unroll
  for (int off = 32; off >= 1; off >>= 1) {
#pragma unroll
    for (int e = 0; e < 17; e++) acc[e] += __shfl_xor(acc[e], off, 64);
  }
  int wid = tid >> 6, lane = tid & 63;
  if (lane == 0) {
#pragma unroll
    for (int e = 0; e < 17; e++) red[wid][e] = acc[e];
  }
  __syncthreads();
  if (tid == 0) {
    float a[17];
#pragma unroll
    for (int e = 0; e < 17; e++)
      a[e] = red[0][e] + red[1][e] + red[2][e] + red[3][e];
    float m = a[0];
#pragma unroll
    for (int e = 1; e < 16; e++) m = fmaxf(m, a[e]);
    float p[16], s = 0.f;
#pragma unroll
    for (int e = 0; e < 16; e++) { p[e] = expf(a[e] - m); s += p[e]; }
    float inv = 1.f / s;
#pragma unroll
    for (int e = 0; e < 16; e++) p[e] *= inv;
    int ti[4]; float tw[4]; float tsum = 0.f;
#pragma unroll
    for (int k = 0; k < 4; k++) {
      float best = -1.f; int bi = 0;
#pragma unroll
      for (int e = 0; e < 16; e++)
        if (p[e] > best) { best = p[e]; bi = e; }
      ti[k] = bi; tw[k] = best; tsum += best; p[bi] = -2.f;
    }
    float rn = 1.f / tsum;
#pragma unroll
    for (int e = 0; e < 16; e++) logits_out[(long)t * 16 + e] = a[e];
#pragma unroll
    for (int k = 0; k < 4; k++) {
      top_i[t * 4 + k] = ti[k];
      top_w[t * 4 + k] = tw[k] * rn;
    }
    gate_sig[t] = 1.f / (1.f + expf(-a[16]));
  }
}

// ------- build: single block; histogram + prefix + scatter with LDS atomics -------
__global__ __launch_bounds__(256) void k_build(
    const int* __restrict__ top_i, int* __restrict__ counts,
    int* __restrict__ offsets, int* __restrict__ perm, int* __restrict__ slot_of) {
  __shared__ int cnt[E_], cur[E_];
  int tid = threadIdx.x;
  if (tid < E_) cnt[tid] = 0;
  __syncthreads();
  for (int i = tid; i < T_ * 4; i += 256)
    atomicAdd(&cnt[top_i[i]], 1);
  __syncthreads();
  if (tid == 0) {
    int run = 0;
    for (int e = 0; e < E_; e++) {
      int c = cnt[e];
      counts[e] = c;
      offsets[e] = run;
      cur[e] = run;
      run += c;
    }
  }
  __syncthreads();
  for (int i = tid; i < T_ * 4; i += 256) {
    int e = top_i[i];
    int pos = atomicAdd(&cur[e], 1);
    perm[pos] = i >> 2;
    slot_of[i] = pos;
  }
}

// ---------------- m97-style MFMA GEMM: A[M][K] x B^T[N][K] -> Y[M][N] fp32 ----------------
template <int BN, bool GATHER>
__global__ __launch_bounds__(256) void k_gemm(
    const unsigned short* __restrict__ A, int lda,
    const unsigned short* __restrict__ B, long b_stride, int ldb,
    float* __restrict__ Y, int ldy,
    int Mconst, int K,
    const int* __restrict__ counts, const int* __restrict__ offsets,
    const int* __restrict__ perm) {
  int M = Mconst, row_base = 0;
  const unsigned short* Bq = B;
  if (counts) {
    int e = blockIdx.z;
    M = counts[e];
    row_base = offsets[e];
    Bq = B + (long)e * b_stride;
  }
  int mtile = blockIdx.y * 128;
  if (mtile >= M) return;
  int ntile = blockIdx.x * BN;

  __shared__ unsigned short As[128 * 32];
  __shared__ unsigned short Bs[BN * 32];

  int tid = threadIdx.x;
  int wid = tid >> 6, lane = tid & 63;
  int sub = lane >> 2;            // 0..15
  int ks = (lane & 3) << 3;       // shorts, 0/8/16/24

  const unsigned short* aptr[2];
  unsigned short* alds[2];
#pragma unroll
  for (int q = 0; q < 2; q++) {
    int r = q * 64 + wid * 16 + sub;
    int rm = mtile + r;
    if (rm > M - 1) rm = M - 1;
    long arow = GATHER ? (long)perm[row_base + rm] : (long)(row_base + rm);
    aptr[q] = A + arow * (long)lda + ks;
    alds[q] = As + q * 2048 + wid * 512;
  }
  constexpr int BQ = BN / 64;
  const unsigned short* bptr[BQ];
  unsigned short* blds[BQ];
#pragma unroll
  for (int q = 0; q < BQ; q++) {
    int r = q * 64 + wid * 16 + sub;
    bptr[q] = Bq + (long)(ntile + r) * ldb + ks;
    blds[q] = Bs + q * 2048 + wid * 512;
  }

  constexpr int MI = (BN == 128) ? 4 : 2;
  int wr = (BN == 128) ? ((wid >> 1) << 6) : (wid << 5);
  int wc = (BN == 128) ? ((wid & 1) << 6) : 0;
  int fr = lane & 15, quad = lane >> 4;

  f32x4 acc[MI][4];
#pragma unroll
  for (int i = 0; i < MI; i++)
#pragma unroll
    for (int j = 0; j < 4; j++) acc[i][j] = (f32x4){0.f, 0.f, 0.f, 0.f};

  for (int kt = 0; kt < K; kt += 32) {
    __syncthreads();
#pragma unroll
    for (int q = 0; q < 2; q++) gload16(aptr[q] + kt, alds[q]);
#pragma unroll
    for (int q = 0; q < BQ; q++) gload16(bptr[q] + kt, blds[q]);
    __syncthreads();
    short8 af[MI], bf[4];
#pragma unroll
    for (int i = 0; i < MI; i++)
      af[i] = *(const short8*)(&As[(wr + i * 16 + fr) * 32 + quad * 8]);
#pragma unroll
    for (int j = 0; j < 4; j++)
      bf[j] = *(const short8*)(&Bs[(wc + j * 16 + fr) * 32 + quad * 8]);
#pragma unroll
    for (int i = 0; i < MI; i++)
#pragma unroll
      for (int j = 0; j < 4; j++)
        acc[i][j] = __builtin_amdgcn_mfma_f32_16x16x32_bf16(af[i], bf[j], acc[i][j], 0, 0, 0);
  }

#pragma unroll
  for (int i = 0; i < MI; i++) {
    int m0 = mtile + wr + i * 16 + quad * 4;
#pragma unroll
    for (int j = 0; j < 4; j++) {
      int col = ntile + wc + j * 16 + fr;
#pragma unroll
      for (int r = 0; r < 4; r++) {
        int m = m0 + r;
        if (m < M) Y[(long)(row_base + m) * ldy + col] = acc[i][j][r];
      }
    }
  }
}

// ---------------- epilogue: h = silu(g)*u, Y[rows][2N] -> bf16 [rows][N] ----------------
__global__ __launch_bounds__(256) void k_silu_mul(const float* __restrict__ Y,
                                                  unsigned short* __restrict__ Hd,
                                                  int rows, int N) {
  long idx = (long)blockIdx.x * 256 + threadIdx.x;
  long n4 = N >> 2;
  long total = (long)rows * n4;
  if (idx >= total) return;
  long r = idx / n4;
  long c = (idx - r * n4) << 2;
  const float* yr = Y + r * 2 * N;
  float4 g = *(const float4*)(yr + c);
  float4 u = *(const float4*)(yr + N + c);
  ushort4 o;
  o.x = f2bf(g.x / (1.f + expf(-g.x)) * u.x);
  o.y = f2bf(g.y / (1.f + expf(-g.y)) * u.y);
  o.z = f2bf(g.z / (1.f + expf(-g.z)) * u.z);
  o.w = f2bf(g.w / (1.f + expf(-g.w)) * u.w);
  *(ushort4*)(Hd + r * N + c) = o;
}

// ---------------- combine: out = sum_k w*Yd[slot] + sig*shared ----------------
__global__ __launch_bounds__(256) void k_combine(
    const float* __restrict__ Yd, const float* __restrict__ shout,
    const float* __restrict__ gate_sig, const float* __restrict__ top_w,
    const int* __restrict__ slot_of, float* __restrict__ out) {
  int t = blockIdx.x;
  int c = threadIdx.x << 2;
  float4 sh = *(const float4*)(shout + (long)t * H_ + c);
  float gs = gate_sig[t];
  float4 o;
  o.x = gs * sh.x; o.y = gs * sh.y; o.z = gs * sh.z; o.w = gs * sh.w;
#pragma unroll
  for (int k = 0; k < 4; k++) {
    int s = slot_of[t * 4 + k];
    float w = top_w[t * 4 + k];
    float4 v = *(const float4*)(Yd + (long)s * H_ + c);
    o.x += w * v.x; o.y += w * v.y; o.z += w * v.z; o.w += w * v.w;
  }
  *(float4*)(out + (long)t * H_ + c) = o;
}

extern "C" void kernel_launch(void* const* d_in, const int* in_sizes, int n_in,
                              void* d_out, int out_size, void* d_ws, size_t ws_size,
                              hipStream_t stream) {
  const float* x    = (const float*)d_in[0];
  const float* wrt  = (const float*)d_in[1];
  const float* wg   = (const float*)d_in[2];
  const float* wu   = (const float*)d_in[3];
  const float* wd   = (const float*)d_in[4];
  const float* wsg  = (const float*)d_in[5];
  const float* wsu  = (const float*)d_in[6];
  const float* wsd  = (const float*)d_in[7];
  const float* wshg = (const float*)d_in[8];
  float* out = (float*)d_out;
  float* logits_out = out + (long)T_ * H_;

  char* ws = (char*)d_ws;
  size_t off = 0;
  auto take = [&](size_t bytes) -> void* {
    void* p = ws + off;
    off += (bytes + 255) & ~(size_t)255;
    return p;
  };

  unsigned short* XB    = (unsigned short*)take((size_t)T_ * H_ * 2);
  unsigned short* WGUT  = (unsigned short*)take((size_t)E_ * 2 * I_ * H_ * 2);  // [e][n=2I][h]
  unsigned short* WDT   = (unsigned short*)take((size_t)E_ * H_ * I_ * 2);      // [e][n=H][k=I]
  unsigned short* WSGUT = (unsigned short*)take((size_t)2 * IS_ * H_ * 2);      // [n=2IS][h]
  unsigned short* WSDT  = (unsigned short*)take((size_t)H_ * IS_ * 2);          // [n=H][k=IS]
  float*          YBUF  = (float*)take((size_t)4096 * 1024 * 4);                // reused 3x
  unsigned short* HSB   = (unsigned short*)take((size_t)T_ * IS_ * 2);
  float*          SHOUT = (float*)take((size_t)T_ * H_ * 4);
  unsigned short* HB    = (unsigned short*)take((size_t)4096 * I_ * 2);
  int*   counts   = (int*)take(64);
  int*   offsets  = (int*)take(64);
  int*   top_i    = (int*)take((size_t)T_ * 4 * 4);
  float* top_w    = (float*)take((size_t)T_ * 4 * 4);
  int*   perm     = (int*)take((size_t)4096 * 4);
  int*   slot_of  = (int*)take((size_t)4096 * 4);
  float* gate_sig = (float*)take((size_t)T_ * 4);

  k_router<<<T_, 256, 0, stream>>>(x, wrt, wshg, XB, logits_out, top_i, top_w, gate_sig);
  k_build<<<1, 256, 0, stream>>>(top_i, counts, offsets, perm, slot_of);

  // weight transposes to [N][K] bf16 (64x64 tiles)
  k_transpose_cvt<<<dim3(I_ / 64, H_ / 64, E_), 256, 0, stream>>>(
      wg, WGUT, I_, H_, (long)H_ * I_, (long)2 * I_ * H_);
  k_transpose_cvt<<<dim3(I_ / 64, H_ / 64, E_), 256, 0, stream>>>(
      wu, WGUT + (size_t)I_ * H_, I_, H_, (long)H_ * I_, (long)2 * I_ * H_);
  k_transpose_cvt<<<dim3(H_ / 64, I_ / 64, E_), 256, 0, stream>>>(
      wd, WDT, H_, I_, (long)I_ * H_, (long)H_ * I_);
  k_transpose_cvt<<<dim3(IS_ / 64, H_ / 64, 1), 256, 0, stream>>>(
      wsg, WSGUT, IS_, H_, 0, 0);
  k_transpose_cvt<<<dim3(IS_ / 64, H_ / 64, 1), 256, 0, stream>>>(
      wsu, WSGUT + (size_t)IS_ * H_, IS_, H_, 0, 0);
  k_transpose_cvt<<<dim3(H_ / 64, IS_ / 64, 1), 256, 0, stream>>>(
      wsd, WSDT, H_, IS_, 0, 0);

  // shared gate/up: M=1024, N=4096, K=1024 -> YBUF [1024][4096]
  k_gemm<128, false><<<dim3(4096 / 128, 1024 / 128, 1), 256, 0, stream>>>(
      XB, H_, WSGUT, 0, H_, YBUF, 4096, T_, H_, nullptr, nullptr, nullptr);
  k_silu_mul<<<2048, 256, 0, stream>>>(YBUF, HSB, T_, IS_);

  // shared down: M=1024, N=1024, K=2048 -> SHOUT  (BN=64 for 2x the blocks)
  k_gemm<64, false><<<dim3(1024 / 64, 1024 / 128, 1), 256, 0, stream>>>(
      HSB, IS_, WSDT, 0, IS_, SHOUT, H_, T_, IS_, nullptr, nullptr, nullptr);

  // expert gate/up (gathered rows): N=1024, K=1024 -> YBUF [4096 slots][1024]
  k_gemm<128, true><<<dim3(1024 / 128, 8, E_), 256, 0, stream>>>(
      XB, H_, WGUT, (long)2 * I_ * H_, H_, YBUF, 1024, 0, H_, counts, offsets, perm);
  k_silu_mul<<<2048, 256, 0, stream>>>(YBUF, HB, 4096, I_);

  // expert down: N=1024, K=512 -> YBUF [4096 slots][1024]
  k_gemm<128, false><<<dim3(1024 / 128, 8, E_), 256, 0, stream>>>(
      HB, I_, WDT, (long)H_ * I_, I_, YBUF, 1024, 0, I_, counts, offsets, perm);

  k_combine<<<T_, 256, 0, stream>>>(YBUF, SHOUT, gate_sig, top_w, slot_of, out);
}

// Round 6
// 316.676 us; speedup vs baseline: 1.3527x; 1.1013x over previous
//
#include <hip/hip_runtime.h>
#include <hip/hip_bf16.h>

#define T_ 1024
#define H_ 1024
#define I_ 512
#define IS_ 2048
#define E_ 16

typedef __attribute__((ext_vector_type(8))) short short8;
typedef __attribute__((ext_vector_type(4))) float f32x4;

__device__ __forceinline__ unsigned short f2bf(float f) {
  unsigned u = __builtin_bit_cast(unsigned, f);
  unsigned r = (u + 0x7fffu + ((u >> 16) & 1u)) >> 16;
  return (unsigned short)r;
}

__device__ __forceinline__ void gload16(const void* g, void* l) {
  __builtin_amdgcn_global_load_lds(
      (const __attribute__((address_space(1))) unsigned int*)g,
      (__attribute__((address_space(3))) unsigned int*)l, 16, 0, 0);
}

// ------------- transpose tile body: src fp32 [b][R][C] -> dst bf16 [b][C][R] -------------
__device__ __forceinline__ void transpose_tile(
    const float* __restrict__ src, unsigned short* __restrict__ dst,
    int C, int dld, long sbs, long dbs, int bx, int by, int bz) {
  __shared__ unsigned short tile[64 * 72];
  const float* s = src + (long)bz * sbs + ((long)by * 64) * C + bx * 64;
  int cgrp = threadIdx.x & 15, rgrp = threadIdx.x >> 4;
  int c = cgrp << 2, r0 = rgrp << 2;
  const float* sp = s + (long)r0 * C + c;
  float4 v0 = *(const float4*)(sp);
  float4 v1 = *(const float4*)(sp + C);
  float4 v2 = *(const float4*)(sp + 2 * C);
  float4 v3 = *(const float4*)(sp + 3 * C);
  ushort4 w;
  w = (ushort4){f2bf(v0.x), f2bf(v1.x), f2bf(v2.x), f2bf(v3.x)};
  *(ushort4*)&tile[(c + 0) * 72 + r0] = w;
  w = (ushort4){f2bf(v0.y), f2bf(v1.y), f2bf(v2.y), f2bf(v3.y)};
  *(ushort4*)&tile[(c + 1) * 72 + r0] = w;
  w = (ushort4){f2bf(v0.z), f2bf(v1.z), f2bf(v2.z), f2bf(v3.z)};
  *(ushort4*)&tile[(c + 2) * 72 + r0] = w;
  w = (ushort4){f2bf(v0.w), f2bf(v1.w), f2bf(v2.w), f2bf(v3.w)};
  *(ushort4*)&tile[(c + 3) * 72 + r0] = w;
  __syncthreads();
  int orr = threadIdx.x >> 2;        // dst row (src col)
  int ks = (threadIdx.x & 3) << 4;   // 16 shorts per thread
  uint4 o0 = *(const uint4*)&tile[orr * 72 + ks];
  uint4 o1 = *(const uint4*)&tile[orr * 72 + ks + 8];
  unsigned short* d = dst + (long)bz * dbs + (long)(bx * 64 + orr) * dld + by * 64 + ks;
  *(uint4*)d = o0;
  *(uint4*)(d + 8) = o1;
}

// All 6 weight transposes in one launch (7680 blocks).
__global__ __launch_bounds__(256) void k_transpose_all(
    const float* __restrict__ wg, const float* __restrict__ wu,
    const float* __restrict__ wd, const float* __restrict__ wsg,
    const float* __restrict__ wsu, const float* __restrict__ wsd,
    unsigned short* __restrict__ WGUT, unsigned short* __restrict__ WDT,
    unsigned short* __restrict__ WSGUT, unsigned short* __restrict__ WSDT) {
  int id = blockIdx.x;
  if (id < 4096) {                       // wg / wu: nx=8, ny=16, nb=16
    const float* s = id < 2048 ? wg : wu;
    unsigned short* dd = id < 2048 ? WGUT : WGUT + (size_t)I_ * H_;
    int l = id & 2047;
    int bz = l >> 7, r = l & 127;
    transpose_tile(s, dd, I_, H_, (long)H_ * I_, (long)2 * I_ * H_, r & 7, r >> 3, bz);
  } else if (id < 6144) {                // wd: nx=16, ny=8, nb=16
    int l = id - 4096;
    int bz = l >> 7, r = l & 127;
    transpose_tile(wd, WDT, H_, I_, (long)I_ * H_, (long)H_ * I_, r & 15, r >> 4, bz);
  } else if (id < 7168) {                // wsg / wsu: nx=32, ny=16
    int l = id - 6144;
    const float* s = l < 512 ? wsg : wsu;
    unsigned short* dd = l < 512 ? WSGUT : WSGUT + (size_t)IS_ * H_;
    l &= 511;
    transpose_tile(s, dd, IS_, H_, 0, 0, l & 31, l >> 5, 0);
  } else {                               // wsd: nx=16, ny=32
    int l = id - 7168;
    transpose_tile(wsd, WSDT, H_, IS_, 0, 0, l & 15, l >> 4, 0);
  }
}

// ------- router: logits fp32, softmax, top4, renorm, shared gate; fused x->bf16 -------
// NO global atomics (4096 same-line device atomics serialized at ~57us in R1/R2).
__global__ __launch_bounds__(256) void k_router(
    const float* __restrict__ x, const float* __restrict__ wr,
    const float* __restrict__ wshg, unsigned short* __restrict__ xb,
    float* __restrict__ logits_out,
    int* __restrict__ top_i, float* __restrict__ top_w,
    float* __restrict__ gate_sig) {
  __shared__ float red[4][17];
  int t = blockIdx.x, tid = threadIdx.x;
  int h0 = tid << 2;
  float acc[17];
#pragma unroll
  for (int e = 0; e < 17; e++) acc[e] = 0.f;
  float4 xv = *(const float4*)(x + (long)t * H_ + h0);
  float4 wsh = *(const float4*)(wshg + h0);
  ushort4 xo;
  xo.x = f2bf(xv.x); xo.y = f2bf(xv.y); xo.z = f2bf(xv.z); xo.w = f2bf(xv.w);
  *(ushort4*)(xb + (long)t * H_ + h0) = xo;
  float xs[4] = {xv.x, xv.y, xv.z, xv.w};
  float ws[4] = {wsh.x, wsh.y, wsh.z, wsh.w};
#pragma unroll
  for (int j = 0; j < 4; j++) {
    const float4* w4 = (const float4*)(wr + (long)(h0 + j) * 16);
    float4 w0 = w4[0], w1 = w4[1], w2 = w4[2], w3 = w4[3];
    float xvj = xs[j];
    acc[0] += xvj * w0.x; acc[1] += xvj * w0.y; acc[2] += xvj * w0.z; acc[3] += xvj * w0.w;
    acc[4] += xvj * w1.x; acc[5] += xvj * w1.y; acc[6] += xvj * w1.z; acc[7] += xvj * w1.w;
    acc[8] += xvj * w2.x; acc[9] += xvj * w2.y; acc[10] += xvj * w2.z; acc[11] += xvj * w2.w;
    acc[12] += xvj * w3.x; acc[13] += xvj * w3.y; acc[14] += xvj * w3.z; acc[15] += xvj * w3.w;
    acc[16] += xvj * ws[j];
  }
#pragma unroll
  for (int off = 32; off >= 1; off >>= 1) {
#pragma unroll
    for (int e = 0; e < 17; e++) acc[e] += __shfl_xor(acc[e], off, 64);
  }
  int wid = tid >> 6, lane = tid & 63;
  if (lane == 0) {
#pragma unroll
    for (int e = 0; e < 17; e++) red[wid][e] = acc[e];
  }
  __syncthreads();
  if (tid == 0) {
    float a[17];
#pragma unroll
    for (int e = 0; e < 17; e++)
      a[e] = red[0][e] + red[1][e] + red[2][e] + red[3][e];
    float m = a[0];
#pragma unroll
    for (int e = 1; e < 16; e++) m = fmaxf(m, a[e]);
    float p[16], s = 0.f;
#pragma unroll
    for (int e = 0; e < 16; e++) { p[e] = expf(a[e] - m); s += p[e]; }
    float inv = 1.f / s;
#pragma unroll
    for (int e = 0; e < 16; e++) p[e] *= inv;
    int ti[4]; float tw[4]; float tsum = 0.f;
#pragma unroll
    for (int k = 0; k < 4; k++) {
      float best = -1.f; int bi = 0;
#pragma unroll
      for (int e = 0; e < 16; e++)
        if (p[e] > best) { best = p[e]; bi = e; }
      ti[k] = bi; tw[k] = best; tsum += best; p[bi] = -2.f;
    }
    float rn = 1.f / tsum;
#pragma unroll
    for (int e = 0; e < 16; e++) logits_out[(long)t * 16 + e] = a[e];
#pragma unroll
    for (int k = 0; k < 4; k++) {
      top_i[t * 4 + k] = ti[k];
      top_w[t * 4 + k] = tw[k] * rn;
    }
    gate_sig[t] = 1.f / (1.f + expf(-a[16]));
  }
}

// ------- build: single block; histogram + prefix + scatter with LDS atomics -------
__global__ __launch_bounds__(256) void k_build(
    const int* __restrict__ top_i, int* __restrict__ counts,
    int* __restrict__ offsets, int* __restrict__ perm, int* __restrict__ slot_of) {
  __shared__ int cnt[E_], cur[E_];
  int tid = threadIdx.x;
  if (tid < E_) cnt[tid] = 0;
  __syncthreads();
  for (int i = tid; i < T_ * 4; i += 256)
    atomicAdd(&cnt[top_i[i]], 1);
  __syncthreads();
  if (tid == 0) {
    int run = 0;
    for (int e = 0; e < E_; e++) {
      int c = cnt[e];
      counts[e] = c;
      offsets[e] = run;
      cur[e] = run;
      run += c;
    }
  }
  __syncthreads();
  for (int i = tid; i < T_ * 4; i += 256) {
    int e = top_i[i];
    int pos = atomicAdd(&cur[e], 1);
    perm[pos] = i >> 2;
    slot_of[i] = pos;
  }
}

// ---------------- 128x128 MFMA GEMM core, XOR-swizzled LDS (conflict-free b128 reads) ----
// A[M][K] x B^T[N][K] -> Y[M tile][N tile]. B is the full (per-expert) matrix base;
// ntile is applied exactly ONCE here (round-5 bug: call sites also pre-offset B).
__device__ __forceinline__ void gemm_core(
    const unsigned short* __restrict__ A, int lda,
    const unsigned short* __restrict__ B, int ldb,
    float* __restrict__ Y, int ldy,
    int M, int row_base, int K, int mtile, int ntile,
    const int* __restrict__ perm) {
  __shared__ unsigned short As[128 * 32];
  __shared__ unsigned short Bs[128 * 32];
  int tid = threadIdx.x;
  int wid = tid >> 6, lane = tid & 63;
  int sub = lane >> 2;                      // row-within-16
  int ks = (((lane & 3) ^ ((sub >> 1) & 3)) << 3);  // swizzled k-chunk (shorts)

  const unsigned short* aptr[2];
  unsigned short* alds[2];
#pragma unroll
  for (int q = 0; q < 2; q++) {
    int r = q * 64 + wid * 16 + sub;
    int rm = mtile + r;
    if (rm > M - 1) rm = M - 1;
    long arow = perm ? (long)perm[row_base + rm] : (long)(row_base + rm);
    aptr[q] = A + arow * (long)lda + ks;
    alds[q] = As + q * 2048 + wid * 512;
  }
  const unsigned short* bptr[2];
  unsigned short* blds[2];
#pragma unroll
  for (int q = 0; q < 2; q++) {
    int r = q * 64 + wid * 16 + sub;
    bptr[q] = B + (long)(ntile + r) * ldb + ks;
    blds[q] = Bs + q * 2048 + wid * 512;
  }

  int fr = lane & 15, quad = lane >> 4;
  int fslot = (quad ^ ((fr >> 1) & 3)) << 3;  // swizzled read slot
  int wr = (wid >> 1) << 6, wc = (wid & 1) << 6;

  f32x4 acc[4][4];
#pragma unroll
  for (int i = 0; i < 4; i++)
#pragma unroll
    for (int j = 0; j < 4; j++) acc[i][j] = (f32x4){0.f, 0.f, 0.f, 0.f};

  for (int kt = 0; kt < K; kt += 32) {
    __syncthreads();
    gload16(aptr[0] + kt, alds[0]);
    gload16(aptr[1] + kt, alds[1]);
    gload16(bptr[0] + kt, blds[0]);
    gload16(bptr[1] + kt, blds[1]);
    __syncthreads();
    short8 af[4], bf[4];
#pragma unroll
    for (int i = 0; i < 4; i++)
      af[i] = *(const short8*)(&As[(wr + i * 16 + fr) * 32 + fslot]);
#pragma unroll
    for (int j = 0; j < 4; j++)
      bf[j] = *(const short8*)(&Bs[(wc + j * 16 + fr) * 32 + fslot]);
#pragma unroll
    for (int i = 0; i < 4; i++)
#pragma unroll
      for (int j = 0; j < 4; j++)
        acc[i][j] = __builtin_amdgcn_mfma_f32_16x16x32_bf16(af[i], bf[j], acc[i][j], 0, 0, 0);
  }

#pragma unroll
  for (int i = 0; i < 4; i++) {
    int m0 = mtile + wr + i * 16 + quad * 4;
#pragma unroll
    for (int j = 0; j < 4; j++) {
      int col = ntile + wc + j * 16 + fr;
#pragma unroll
      for (int r = 0; r < 4; r++) {
        int m = m0 + r;
        if (m < M) Y[(long)(row_base + m) * ldy + col] = acc[i][j][r];
      }
    }
  }
}

// Fused gate/up GEMM: z=0 shared expert (N=4096), z=1..16 routed experts (N=1024, gathered).
__global__ __launch_bounds__(256) void k_gemm_gu(
    const unsigned short* __restrict__ XB,
    const unsigned short* __restrict__ WSGUT, float* __restrict__ YS,
    const unsigned short* __restrict__ WGUT, float* __restrict__ YE,
    const int* __restrict__ counts, const int* __restrict__ offsets,
    const int* __restrict__ perm) {
  int z = blockIdx.z;
  int ntile = blockIdx.x * 128, mtile = blockIdx.y * 128;
  if (z == 0) {
    gemm_core(XB, H_, WSGUT, H_, YS, 4096, T_, 0, H_, mtile, ntile, nullptr);
  } else {
    if (ntile >= 1024) return;
    int e = z - 1;
    int M = counts[e];
    if (mtile >= M) return;
    gemm_core(XB, H_, WGUT + (long)e * 2 * I_ * H_, H_, YE, 1024,
              M, offsets[e], H_, mtile, ntile, perm);
  }
}

// Fused down GEMM: z=0 shared (K=2048), z=1..16 routed (K=512, rows already packed).
__global__ __launch_bounds__(256) void k_gemm_dn(
    const unsigned short* __restrict__ HSB, const unsigned short* __restrict__ WSDT,
    float* __restrict__ SHOUT,
    const unsigned short* __restrict__ HB, const unsigned short* __restrict__ WDT,
    float* __restrict__ YD,
    const int* __restrict__ counts, const int* __restrict__ offsets) {
  int z = blockIdx.z;
  int ntile = blockIdx.x * 128, mtile = blockIdx.y * 128;
  if (z == 0) {
    gemm_core(HSB, IS_, WSDT, IS_, SHOUT, H_, T_, 0, IS_, mtile, ntile, nullptr);
  } else {
    int e = z - 1;
    int M = counts[e];
    if (mtile >= M) return;
    gemm_core(HB, I_, WDT + (long)e * H_ * I_, I_, YD, H_,
              M, offsets[e], I_, mtile, ntile, nullptr);
  }
}

// ---------------- fused silu epilogues for shared + expert halves ----------------
__global__ __launch_bounds__(256) void k_silu_all(
    const float* __restrict__ YS, unsigned short* __restrict__ HSB,
    const float* __restrict__ YE, unsigned short* __restrict__ HB) {
  int bid = blockIdx.x;
  float4 g, u;
  unsigned short* dp;
  if (bid < 2048) {   // shared: [1024][4096] -> HSB [1024][2048]
    long idx = (long)bid * 256 + threadIdx.x;
    long r = idx >> 9;              // /512
    long c = (idx & 511) << 2;
    const float* yr = YS + r * 4096;
    g = *(const float4*)(yr + c);
    u = *(const float4*)(yr + 2048 + c);
    dp = HSB + r * 2048 + c;
  } else {            // expert: [4096][1024] -> HB [4096][512]
    long idx = (long)(bid - 2048) * 256 + threadIdx.x;
    long r = idx >> 7;              // /128
    long c = (idx & 127) << 2;
    const float* yr = YE + r * 1024;
    g = *(const float4*)(yr + c);
    u = *(const float4*)(yr + 512 + c);
    dp = HB + r * 512 + c;
  }
  ushort4 o;
  o.x = f2bf(g.x / (1.f + expf(-g.x)) * u.x);
  o.y = f2bf(g.y / (1.f + expf(-g.y)) * u.y);
  o.z = f2bf(g.z / (1.f + expf(-g.z)) * u.z);
  o.w = f2bf(g.w / (1.f + expf(-g.w)) * u.w);
  *(ushort4*)dp = o;
}

// ---------------- combine: out = sum_k w*Yd[slot] + sig*shared ----------------
__global__ __launch_bounds__(256) void k_combine(
    const float* __restrict__ Yd, const float* __restrict__ shout,
    const float* __restrict__ gate_sig, const float* __restrict__ top_w,
    const int* __restrict__ slot_of, float* __restrict__ out) {
  int t = blockIdx.x;
  int c = threadIdx.x << 2;
  float4 sh = *(const float4*)(shout + (long)t * H_ + c);
  float gs = gate_sig[t];
  float4 o;
  o.x = gs * sh.x; o.y = gs * sh.y; o.z = gs * sh.z; o.w = gs * sh.w;
#pragma unroll
  for (int k = 0; k < 4; k++) {
    int s = slot_of[t * 4 + k];
    float w = top_w[t * 4 + k];
    float4 v = *(const float4*)(Yd + (long)s * H_ + c);
    o.x += w * v.x; o.y += w * v.y; o.z += w * v.z; o.w += w * v.w;
  }
  *(float4*)(out + (long)t * H_ + c) = o;
}

extern "C" void kernel_launch(void* const* d_in, const int* in_sizes, int n_in,
                              void* d_out, int out_size, void* d_ws, size_t ws_size,
                              hipStream_t stream) {
  const float* x    = (const float*)d_in[0];
  const float* wrt  = (const float*)d_in[1];
  const float* wg   = (const float*)d_in[2];
  const float* wu   = (const float*)d_in[3];
  const float* wd   = (const float*)d_in[4];
  const float* wsg  = (const float*)d_in[5];
  const float* wsu  = (const float*)d_in[6];
  const float* wsd  = (const float*)d_in[7];
  const float* wshg = (const float*)d_in[8];
  float* out = (float*)d_out;
  float* logits_out = out + (long)T_ * H_;

  char* ws = (char*)d_ws;
  size_t off = 0;
  auto take = [&](size_t bytes) -> void* {
    void* p = ws + off;
    off += (bytes + 255) & ~(size_t)255;
    return p;
  };

  unsigned short* XB    = (unsigned short*)take((size_t)T_ * H_ * 2);
  unsigned short* WGUT  = (unsigned short*)take((size_t)E_ * 2 * I_ * H_ * 2);  // [e][n=2I][h]
  unsigned short* WDT   = (unsigned short*)take((size_t)E_ * H_ * I_ * 2);      // [e][n=H][k=I]
  unsigned short* WSGUT = (unsigned short*)take((size_t)2 * IS_ * H_ * 2);      // [n=2IS][h]
  unsigned short* WSDT  = (unsigned short*)take((size_t)H_ * IS_ * 2);          // [n=H][k=IS]
  float*          YS    = (float*)take((size_t)T_ * 4096 * 4);                  // shared g|u
  float*          YE    = (float*)take((size_t)4096 * 1024 * 4);                // expert g|u
  unsigned short* HSB   = (unsigned short*)take((size_t)T_ * IS_ * 2);
  float*          SHOUT = (float*)take((size_t)T_ * H_ * 4);
  unsigned short* HB    = (unsigned short*)take((size_t)4096 * I_ * 2);
  int*   counts   = (int*)take(64);
  int*   offsets  = (int*)take(64);
  int*   top_i    = (int*)take((size_t)T_ * 4 * 4);
  float* top_w    = (float*)take((size_t)T_ * 4 * 4);
  int*   perm     = (int*)take((size_t)4096 * 4);
  int*   slot_of  = (int*)take((size_t)4096 * 4);
  float* gate_sig = (float*)take((size_t)T_ * 4);
  float* YD = YS;  // expert down output reuses YS (free after k_silu_all)

  k_router<<<T_, 256, 0, stream>>>(x, wrt, wshg, XB, logits_out, top_i, top_w, gate_sig);
  k_build<<<1, 256, 0, stream>>>(top_i, counts, offsets, perm, slot_of);
  k_transpose_all<<<7680, 256, 0, stream>>>(wg, wu, wd, wsg, wsu, wsd,
                                            WGUT, WDT, WSGUT, WSDT);

  // fused gate/up: z=0 shared (32x8 live), z>=1 experts (~300 live)
  k_gemm_gu<<<dim3(32, 8, 17), 256, 0, stream>>>(XB, WSGUT, YS, WGUT, YE,
                                                 counts, offsets, perm);
  k_silu_all<<<4096, 256, 0, stream>>>(YS, HSB, YE, HB);

  // fused down: z=0 shared (8x8), z>=1 experts (~300 live)
  k_gemm_dn<<<dim3(8, 8, 17), 256, 0, stream>>>(HSB, WSDT, SHOUT, HB, WDT, YD,
                                                counts, offsets);

  k_combine<<<T_, 256, 0, stream>>>(YD, SHOUT, gate_sig, top_w, slot_of, out);
}

// Round 7
// 289.111 us; speedup vs baseline: 1.4816x; 1.0953x over previous
//
#include <hip/hip_runtime.h>
#include <hip/hip_bf16.h>

#define T_ 1024
#define H_ 1024
#define I_ 512
#define IS_ 2048
#define E_ 16

typedef __attribute__((ext_vector_type(8))) short short8;
typedef __attribute__((ext_vector_type(4))) float f32x4;

__device__ __forceinline__ unsigned short f2bf(float f) {
  unsigned u = __builtin_bit_cast(unsigned, f);
  unsigned r = (u + 0x7fffu + ((u >> 16) & 1u)) >> 16;
  return (unsigned short)r;
}

__device__ __forceinline__ void gload16(const void* g, void* l) {
  __builtin_amdgcn_global_load_lds(
      (const __attribute__((address_space(1))) unsigned int*)g,
      (__attribute__((address_space(3))) unsigned int*)l, 16, 0, 0);
}

// ------------- transpose tile body: src fp32 [b][R][C] -> dst bf16 [b][C][R] -------------
__device__ __forceinline__ void transpose_tile(
    const float* __restrict__ src, unsigned short* __restrict__ dst,
    int C, int dld, long sbs, long dbs, int bx, int by, int bz) {
  __shared__ unsigned short tile[64 * 72];
  const float* s = src + (long)bz * sbs + ((long)by * 64) * C + bx * 64;
  int cgrp = threadIdx.x & 15, rgrp = threadIdx.x >> 4;
  int c = cgrp << 2, r0 = rgrp << 2;
  const float* sp = s + (long)r0 * C + c;
  float4 v0 = *(const float4*)(sp);
  float4 v1 = *(const float4*)(sp + C);
  float4 v2 = *(const float4*)(sp + 2 * C);
  float4 v3 = *(const float4*)(sp + 3 * C);
  ushort4 w;
  w = (ushort4){f2bf(v0.x), f2bf(v1.x), f2bf(v2.x), f2bf(v3.x)};
  *(ushort4*)&tile[(c + 0) * 72 + r0] = w;
  w = (ushort4){f2bf(v0.y), f2bf(v1.y), f2bf(v2.y), f2bf(v3.y)};
  *(ushort4*)&tile[(c + 1) * 72 + r0] = w;
  w = (ushort4){f2bf(v0.z), f2bf(v1.z), f2bf(v2.z), f2bf(v3.z)};
  *(ushort4*)&tile[(c + 2) * 72 + r0] = w;
  w = (ushort4){f2bf(v0.w), f2bf(v1.w), f2bf(v2.w), f2bf(v3.w)};
  *(ushort4*)&tile[(c + 3) * 72 + r0] = w;
  __syncthreads();
  int orr = threadIdx.x >> 2;
  int ks = (threadIdx.x & 3) << 4;
  uint4 o0 = *(const uint4*)&tile[orr * 72 + ks];
  uint4 o1 = *(const uint4*)&tile[orr * 72 + ks + 8];
  unsigned short* d = dst + (long)bz * dbs + (long)(bx * 64 + orr) * dld + by * 64 + ks;
  *(uint4*)d = o0;
  *(uint4*)(d + 8) = o1;
}

// ---- pre: blocks 0..1023 = router (fused x->bf16, NO global atomics);
//           blocks 1024..8703 = all 6 weight transposes ----
__global__ __launch_bounds__(256) void k_pre(
    const float* __restrict__ x, const float* __restrict__ wr,
    const float* __restrict__ wshg,
    const float* __restrict__ wg, const float* __restrict__ wu,
    const float* __restrict__ wd, const float* __restrict__ wsg,
    const float* __restrict__ wsu, const float* __restrict__ wsd,
    unsigned short* __restrict__ xb, float* __restrict__ logits_out,
    int* __restrict__ top_i, float* __restrict__ top_w, float* __restrict__ gate_sig,
    unsigned short* __restrict__ WGUT, unsigned short* __restrict__ WDT,
    unsigned short* __restrict__ WSGUT, unsigned short* __restrict__ WSDT) {
  __shared__ float red[4][17];
  int id = blockIdx.x;
  if (id >= T_) {
    id -= T_;
    if (id < 4096) {
      const float* s = id < 2048 ? wg : wu;
      unsigned short* dd = id < 2048 ? WGUT : WGUT + (size_t)I_ * H_;
      int l = id & 2047;
      int bz = l >> 7, r = l & 127;
      transpose_tile(s, dd, I_, H_, (long)H_ * I_, (long)2 * I_ * H_, r & 7, r >> 3, bz);
    } else if (id < 6144) {
      int l = id - 4096;
      int bz = l >> 7, r = l & 127;
      transpose_tile(wd, WDT, H_, I_, (long)I_ * H_, (long)H_ * I_, r & 15, r >> 4, bz);
    } else if (id < 7168) {
      int l = id - 6144;
      const float* s = l < 512 ? wsg : wsu;
      unsigned short* dd = l < 512 ? WSGUT : WSGUT + (size_t)IS_ * H_;
      l &= 511;
      transpose_tile(s, dd, IS_, H_, 0, 0, l & 31, l >> 5, 0);
    } else {
      int l = id - 7168;
      transpose_tile(wsd, WSDT, H_, IS_, 0, 0, l & 15, l >> 4, 0);
    }
    return;
  }
  int t = id, tid = threadIdx.x;
  int h0 = tid << 2;
  float acc[17];
#pragma unroll
  for (int e = 0; e < 17; e++) acc[e] = 0.f;
  float4 xv = *(const float4*)(x + (long)t * H_ + h0);
  float4 wsh = *(const float4*)(wshg + h0);
  ushort4 xo;
  xo.x = f2bf(xv.x); xo.y = f2bf(xv.y); xo.z = f2bf(xv.z); xo.w = f2bf(xv.w);
  *(ushort4*)(xb + (long)t * H_ + h0) = xo;
  float xs[4] = {xv.x, xv.y, xv.z, xv.w};
  float ws[4] = {wsh.x, wsh.y, wsh.z, wsh.w};
#pragma unroll
  for (int j = 0; j < 4; j++) {
    const float4* w4 = (const float4*)(wr + (long)(h0 + j) * 16);
    float4 w0 = w4[0], w1 = w4[1], w2 = w4[2], w3 = w4[3];
    float xvj = xs[j];
    acc[0] += xvj * w0.x; acc[1] += xvj * w0.y; acc[2] += xvj * w0.z; acc[3] += xvj * w0.w;
    acc[4] += xvj * w1.x; acc[5] += xvj * w1.y; acc[6] += xvj * w1.z; acc[7] += xvj * w1.w;
    acc[8] += xvj * w2.x; acc[9] += xvj * w2.y; acc[10] += xvj * w2.z; acc[11] += xvj * w2.w;
    acc[12] += xvj * w3.x; acc[13] += xvj * w3.y; acc[14] += xvj * w3.z; acc[15] += xvj * w3.w;
    acc[16] += xvj * ws[j];
  }
#pragma unroll
  for (int off = 32; off >= 1; off >>= 1) {
#pragma unroll
    for (int e = 0; e < 17; e++) acc[e] += __shfl_xor(acc[e], off, 64);
  }
  int wid = tid >> 6, lane = tid & 63;
  if (lane == 0) {
#pragma unroll
    for (int e = 0; e < 17; e++) red[wid][e] = acc[e];
  }
  __syncthreads();
  if (tid == 0) {
    float a[17];
#pragma unroll
    for (int e = 0; e < 17; e++)
      a[e] = red[0][e] + red[1][e] + red[2][e] + red[3][e];
    float m = a[0];
#pragma unroll
    for (int e = 1; e < 16; e++) m = fmaxf(m, a[e]);
    float p[16], s = 0.f;
#pragma unroll
    for (int e = 0; e < 16; e++) { p[e] = expf(a[e] - m); s += p[e]; }
    float inv = 1.f / s;
#pragma unroll
    for (int e = 0; e < 16; e++) p[e] *= inv;
    int ti[4]; float tw[4]; float tsum = 0.f;
#pragma unroll
    for (int k = 0; k < 4; k++) {
      float best = -1.f; int bi = 0;
#pragma unroll
      for (int e = 0; e < 16; e++)
        if (p[e] > best) { best = p[e]; bi = e; }
      ti[k] = bi; tw[k] = best; tsum += best; p[bi] = -2.f;
    }
    float rn = 1.f / tsum;
#pragma unroll
    for (int e = 0; e < 16; e++) logits_out[(long)t * 16 + e] = a[e];
#pragma unroll
    for (int k = 0; k < 4; k++) {
      top_i[t * 4 + k] = ti[k];
      top_w[t * 4 + k] = tw[k] * rn;
    }
    gate_sig[t] = 1.f / (1.f + expf(-a[16]));
  }
}

// ------- build: single block; histogram + prefix + scatter with LDS atomics -------
__global__ __launch_bounds__(256) void k_build(
    const int* __restrict__ top_i, int* __restrict__ counts,
    int* __restrict__ offsets, int* __restrict__ perm, int* __restrict__ slot_of) {
  __shared__ int cnt[E_], cur[E_];
  int tid = threadIdx.x;
  if (tid < E_) cnt[tid] = 0;
  __syncthreads();
  for (int i = tid; i < T_ * 4; i += 256)
    atomicAdd(&cnt[top_i[i]], 1);
  __syncthreads();
  if (tid == 0) {
    int run = 0;
    for (int e = 0; e < E_; e++) {
      int c = cnt[e];
      counts[e] = c;
      offsets[e] = run;
      cur[e] = run;
      run += c;
    }
  }
  __syncthreads();
  for (int i = tid; i < T_ * 4; i += 256) {
    int e = top_i[i];
    int pos = atomicAdd(&cur[e], 1);
    perm[pos] = i >> 2;
    slot_of[i] = pos;
  }
}

// ---- gate/up GEMM, BM=64, dual-N (g and u tiles share the A-tile), double-buffered,
//      silu(g)*u fused in-register, writes bf16 H directly. One barrier per K-iter. ----
__global__ __launch_bounds__(256) void k_gemm_gu(
    const unsigned short* __restrict__ XB,
    const unsigned short* __restrict__ WSGUT, const unsigned short* __restrict__ WGUT,
    unsigned short* __restrict__ HSB, unsigned short* __restrict__ HB,
    const int* __restrict__ counts, const int* __restrict__ offsets,
    const int* __restrict__ perm) {
  int z = blockIdx.z;
  int mtile = blockIdx.y * 64;
  int ntile = blockIdx.x * 128;
  int M, row_base, uoff, ldd;
  const unsigned short* B0;
  unsigned short* DST;
  const int* pp;
  if (z == 0) {
    M = T_; row_base = 0; B0 = WSGUT; uoff = IS_;
    DST = HSB; ldd = IS_; pp = nullptr;
  } else {
    if (ntile >= I_) return;
    int e = z - 1;
    M = counts[e];
    if (mtile >= M) return;
    row_base = offsets[e];
    B0 = WGUT + (long)e * 2 * I_ * H_;
    uoff = I_;
    DST = HB; ldd = I_; pp = perm;
  }

  __shared__ unsigned short lds[2][10240];  // As 0..2047 | Bg 2048..6143 | Bu 6144..10239

  int tid = threadIdx.x, wid = tid >> 6, lane = tid & 63;
  int sub = lane >> 2;
  int ksw = ((lane & 3) ^ ((sub >> 1) & 3)) << 3;  // swizzled k-chunk (shorts)

  int rm = mtile + wid * 16 + sub;
  if (rm > M - 1) rm = M - 1;
  long arow = pp ? (long)pp[row_base + rm] : (long)(row_base + rm);
  const unsigned short* aptr = XB + arow * H_ + ksw;
  int a_off = wid * 512;

  const unsigned short* bgptr[2];
  const unsigned short* buptr[2];
  int b_off[2];
#pragma unroll
  for (int q = 0; q < 2; q++) {
    int r = ntile + q * 64 + wid * 16 + sub;
    bgptr[q] = B0 + (long)r * H_ + ksw;
    buptr[q] = B0 + (long)(r + uoff) * H_ + ksw;
    b_off[q] = q * 2048 + wid * 512;
  }

  int fr = lane & 15, quad = lane >> 4;
  int fslot = (quad ^ ((fr >> 1) & 3)) << 3;
  int wm = (wid >> 1) * 32, wn = (wid & 1) * 64;

  f32x4 acc[2][2][4];
#pragma unroll
  for (int h = 0; h < 2; h++)
#pragma unroll
    for (int i = 0; i < 2; i++)
#pragma unroll
      for (int j = 0; j < 4; j++) acc[h][i][j] = (f32x4){0.f, 0.f, 0.f, 0.f};

  const int NK = H_ / 32;
  gload16(aptr, &lds[0][a_off]);
  gload16(bgptr[0], &lds[0][2048 + b_off[0]]);
  gload16(bgptr[1], &lds[0][2048 + b_off[1]]);
  gload16(buptr[0], &lds[0][6144 + b_off[0]]);
  gload16(buptr[1], &lds[0][6144 + b_off[1]]);

  for (int kt = 0; kt < NK; kt++) {
    int cur = kt & 1;
    __syncthreads();  // drains vmcnt -> lds[cur] ready; lds[cur^1] reads done last iter
    if (kt + 1 < NK) {
      int nxt = cur ^ 1, ko = (kt + 1) * 32;
      gload16(aptr + ko, &lds[nxt][a_off]);
      gload16(bgptr[0] + ko, &lds[nxt][2048 + b_off[0]]);
      gload16(bgptr[1] + ko, &lds[nxt][2048 + b_off[1]]);
      gload16(buptr[0] + ko, &lds[nxt][6144 + b_off[0]]);
      gload16(buptr[1] + ko, &lds[nxt][6144 + b_off[1]]);
    }
    const unsigned short* As = &lds[cur][0];
    const unsigned short* Bg = &lds[cur][2048];
    const unsigned short* Bu = &lds[cur][6144];
    short8 af[2], bg[4], bu[4];
#pragma unroll
    for (int i = 0; i < 2; i++)
      af[i] = *(const short8*)(&As[(wm + i * 16 + fr) * 32 + fslot]);
#pragma unroll
    for (int j = 0; j < 4; j++) {
      bg[j] = *(const short8*)(&Bg[(wn + j * 16 + fr) * 32 + fslot]);
      bu[j] = *(const short8*)(&Bu[(wn + j * 16 + fr) * 32 + fslot]);
    }
#pragma unroll
    for (int i = 0; i < 2; i++)
#pragma unroll
      for (int j = 0; j < 4; j++) {
        acc[0][i][j] = __builtin_amdgcn_mfma_f32_16x16x32_bf16(af[i], bg[j], acc[0][i][j], 0, 0, 0);
        acc[1][i][j] = __builtin_amdgcn_mfma_f32_16x16x32_bf16(af[i], bu[j], acc[1][i][j], 0, 0, 0);
      }
  }

#pragma unroll
  for (int i = 0; i < 2; i++) {
    int m0 = mtile + wm + i * 16 + quad * 4;
#pragma unroll
    for (int j = 0; j < 4; j++) {
      int col = ntile + wn + j * 16 + fr;
#pragma unroll
      for (int r = 0; r < 4; r++) {
        int m = m0 + r;
        if (m < M) {
          float g = acc[0][i][j][r], u = acc[1][i][j][r];
          DST[(long)(row_base + m) * ldd + col] = f2bf(g / (1.f + expf(-g)) * u);
        }
      }
    }
  }
}

// ---- down GEMM, BM=64, double-buffered, fp32 out ----
__global__ __launch_bounds__(256) void k_gemm_dn(
    const unsigned short* __restrict__ HSB, const unsigned short* __restrict__ WSDT,
    float* __restrict__ SHOUT,
    const unsigned short* __restrict__ HB, const unsigned short* __restrict__ WDT,
    float* __restrict__ YD,
    const int* __restrict__ counts, const int* __restrict__ offsets) {
  int z = blockIdx.z;
  int mtile = blockIdx.y * 64;
  int ntile = blockIdx.x * 128;
  const unsigned short *A, *B;
  int K, M, rb;
  float* Y;
  if (z == 0) {
    A = HSB; K = IS_; M = T_; rb = 0; B = WSDT; Y = SHOUT;
  } else {
    int e = z - 1;
    M = counts[e];
    if (mtile >= M) return;
    rb = offsets[e];
    A = HB; K = I_; B = WDT + (long)e * H_ * I_; Y = YD;
  }

  __shared__ unsigned short lds[2][6144];  // As 0..2047 | Bs 2048..6143

  int tid = threadIdx.x, wid = tid >> 6, lane = tid & 63;
  int sub = lane >> 2;
  int ksw = ((lane & 3) ^ ((sub >> 1) & 3)) << 3;

  int rm = mtile + wid * 16 + sub;
  if (rm > M - 1) rm = M - 1;
  const unsigned short* aptr = A + (long)(rb + rm) * K + ksw;
  int a_off = wid * 512;

  const unsigned short* bptr[2];
  int b_off[2];
#pragma unroll
  for (int q = 0; q < 2; q++) {
    int r = ntile + q * 64 + wid * 16 + sub;
    bptr[q] = B + (long)r * K + ksw;
    b_off[q] = q * 2048 + wid * 512;
  }

  int fr = lane & 15, quad = lane >> 4;
  int fslot = (quad ^ ((fr >> 1) & 3)) << 3;
  int wm = (wid >> 1) * 32, wn = (wid & 1) * 64;

  f32x4 acc[2][4];
#pragma unroll
  for (int i = 0; i < 2; i++)
#pragma unroll
    for (int j = 0; j < 4; j++) acc[i][j] = (f32x4){0.f, 0.f, 0.f, 0.f};

  const int NK = K / 32;
  gload16(aptr, &lds[0][a_off]);
  gload16(bptr[0], &lds[0][2048 + b_off[0]]);
  gload16(bptr[1], &lds[0][2048 + b_off[1]]);

  for (int kt = 0; kt < NK; kt++) {
    int cur = kt & 1;
    __syncthreads();
    if (kt + 1 < NK) {
      int nxt = cur ^ 1, ko = (kt + 1) * 32;
      gload16(aptr + ko, &lds[nxt][a_off]);
      gload16(bptr[0] + ko, &lds[nxt][2048 + b_off[0]]);
      gload16(bptr[1] + ko, &lds[nxt][2048 + b_off[1]]);
    }
    const unsigned short* As = &lds[cur][0];
    const unsigned short* Bs = &lds[cur][2048];
    short8 af[2], bf[4];
#pragma unroll
    for (int i = 0; i < 2; i++)
      af[i] = *(const short8*)(&As[(wm + i * 16 + fr) * 32 + fslot]);
#pragma unroll
    for (int j = 0; j < 4; j++)
      bf[j] = *(const short8*)(&Bs[(wn + j * 16 + fr) * 32 + fslot]);
#pragma unroll
    for (int i = 0; i < 2; i++)
#pragma unroll
      for (int j = 0; j < 4; j++)
        acc[i][j] = __builtin_amdgcn_mfma_f32_16x16x32_bf16(af[i], bf[j], acc[i][j], 0, 0, 0);
  }

#pragma unroll
  for (int i = 0; i < 2; i++) {
    int m0 = mtile + wm + i * 16 + quad * 4;
#pragma unroll
    for (int j = 0; j < 4; j++) {
      int col = ntile + wn + j * 16 + fr;
#pragma unroll
      for (int r = 0; r < 4; r++) {
        int m = m0 + r;
        if (m < M) Y[(long)(rb + m) * H_ + col] = acc[i][j][r];
      }
    }
  }
}

// ---------------- combine: out = sum_k w*Yd[slot] + sig*shared ----------------
__global__ __launch_bounds__(256) void k_combine(
    const float* __restrict__ Yd, const float* __restrict__ shout,
    const float* __restrict__ gate_sig, const float* __restrict__ top_w,
    const int* __restrict__ slot_of, float* __restrict__ out) {
  int t = blockIdx.x;
  int c = threadIdx.x << 2;
  float4 sh = *(const float4*)(shout + (long)t * H_ + c);
  float gs = gate_sig[t];
  float4 o;
  o.x = gs * sh.x; o.y = gs * sh.y; o.z = gs * sh.z; o.w = gs * sh.w;
#pragma unroll
  for (int k = 0; k < 4; k++) {
    int s = slot_of[t * 4 + k];
    float w = top_w[t * 4 + k];
    float4 v = *(const float4*)(Yd + (long)s * H_ + c);
    o.x += w * v.x; o.y += w * v.y; o.z += w * v.z; o.w += w * v.w;
  }
  *(float4*)(out + (long)t * H_ + c) = o;
}

extern "C" void kernel_launch(void* const* d_in, const int* in_sizes, int n_in,
                              void* d_out, int out_size, void* d_ws, size_t ws_size,
                              hipStream_t stream) {
  const float* x    = (const float*)d_in[0];
  const float* wrt  = (const float*)d_in[1];
  const float* wg   = (const float*)d_in[2];
  const float* wu   = (const float*)d_in[3];
  const float* wd   = (const float*)d_in[4];
  const float* wsg  = (const float*)d_in[5];
  const float* wsu  = (const float*)d_in[6];
  const float* wsd  = (const float*)d_in[7];
  const float* wshg = (const float*)d_in[8];
  float* out = (float*)d_out;
  float* logits_out = out + (long)T_ * H_;

  char* ws = (char*)d_ws;
  size_t off = 0;
  auto take = [&](size_t bytes) -> void* {
    void* p = ws + off;
    off += (bytes + 255) & ~(size_t)255;
    return p;
  };

  unsigned short* XB    = (unsigned short*)take((size_t)T_ * H_ * 2);
  unsigned short* WGUT  = (unsigned short*)take((size_t)E_ * 2 * I_ * H_ * 2);  // [e][g|u rows][h]
  unsigned short* WDT   = (unsigned short*)take((size_t)E_ * H_ * I_ * 2);      // [e][n=H][k=I]
  unsigned short* WSGUT = (unsigned short*)take((size_t)2 * IS_ * H_ * 2);      // [g|u rows][h]
  unsigned short* WSDT  = (unsigned short*)take((size_t)H_ * IS_ * 2);          // [n=H][k=IS]
  float*          YD    = (float*)take((size_t)4096 * H_ * 4);                  // expert down out
  unsigned short* HSB   = (unsigned short*)take((size_t)T_ * IS_ * 2);
  float*          SHOUT = (float*)take((size_t)T_ * H_ * 4);
  unsigned short* HB    = (unsigned short*)take((size_t)4096 * I_ * 2);
  int*   counts   = (int*)take(64);
  int*   offsets  = (int*)take(64);
  int*   top_i    = (int*)take((size_t)T_ * 4 * 4);
  float* top_w    = (float*)take((size_t)T_ * 4 * 4);
  int*   perm     = (int*)take((size_t)4096 * 4);
  int*   slot_of  = (int*)take((size_t)4096 * 4);
  float* gate_sig = (float*)take((size_t)T_ * 4);

  // router (1024 blocks) + all weight transposes (7680 blocks) in one launch
  k_pre<<<8704, 256, 0, stream>>>(x, wrt, wshg, wg, wu, wd, wsg, wsu, wsd,
                                  XB, logits_out, top_i, top_w, gate_sig,
                                  WGUT, WDT, WSGUT, WSDT);
  k_build<<<1, 256, 0, stream>>>(top_i, counts, offsets, perm, slot_of);

  // fused gate/up + silu: z=0 shared (16x16 live), z>=1 experts (x<4, ~y=ceil(M/64))
  k_gemm_gu<<<dim3(16, 16, 17), 256, 0, stream>>>(XB, WSGUT, WGUT, HSB, HB,
                                                  counts, offsets, perm);
  // down: z=0 shared (8x16 live), z>=1 experts
  k_gemm_dn<<<dim3(8, 16, 17), 256, 0, stream>>>(HSB, WSDT, SHOUT, HB, WDT, YD,
                                                 counts, offsets);
  k_combine<<<T_, 256, 0, stream>>>(YD, SHOUT, gate_sig, top_w, slot_of, out);
}